// Round 1
// baseline (531.602 us; speedup 1.0000x reference)
//
#include <hip/hip_runtime.h>

// ---------------- problem constants ----------------
#define gB 2
#define gS 4096
#define gH 32
#define gKVH 8
#define gHID 2048
#define gNC 32            // S / CHK
#define gBS (gB*gS)       // 8192
// D = 64, WIN = 256, CHK = 128, NREP = 4 are hard-coded below.

using bf16x8 = __attribute__((ext_vector_type(8))) short;
using f32x4  = __attribute__((ext_vector_type(4))) float;

__device__ __forceinline__ float bf2f(unsigned short u){
  return __uint_as_float(((unsigned)u) << 16);
}
__device__ __forceinline__ unsigned short f2bf(float f){
  unsigned u = __float_as_uint(f);
  u = (u + 0x7fffu + ((u >> 16) & 1u)) >> 16;   // RNE
  return (unsigned short)u;
}
__device__ __forceinline__ float phi_f(float x){ return x > 0.f ? x + 1.f : __expf(x); } // elu(x)+1

__device__ __forceinline__ void unpack8(uint4 v, unsigned short* o){
  o[0]=(unsigned short)(v.x&0xffffu); o[1]=(unsigned short)(v.x>>16);
  o[2]=(unsigned short)(v.y&0xffffu); o[3]=(unsigned short)(v.y>>16);
  o[4]=(unsigned short)(v.z&0xffffu); o[5]=(unsigned short)(v.z>>16);
  o[6]=(unsigned short)(v.w&0xffffu); o[7]=(unsigned short)(v.w>>16);
}
__device__ __forceinline__ uint4 pack8(const unsigned short* s){
  uint4 v;
  v.x = (unsigned)s[0] | ((unsigned)s[1]<<16);
  v.y = (unsigned)s[2] | ((unsigned)s[3]<<16);
  v.z = (unsigned)s[4] | ((unsigned)s[5]<<16);
  v.w = (unsigned)s[6] | ((unsigned)s[7]<<16);
  return v;
}

// ---------------- f32 -> bf16 convert ----------------
__global__ void cvt_kernel(const float* __restrict__ in, unsigned short* __restrict__ out, int n){
  int stride = gridDim.x * blockDim.x;
  for (int i = blockIdx.x*blockDim.x + threadIdx.x; i*4 < n; i += stride){
    float4 v = *(const float4*)(in + (size_t)i*4);
    ushort4 o;
    o.x = f2bf(v.x); o.y = f2bf(v.y); o.z = f2bf(v.z); o.w = f2bf(v.w);
    *(ushort4*)(out + (size_t)i*4) = o;
  }
}

// ---------------- GEMM: C[M,N] = A[M,K] * B[N,K]^T, bf16 in, f32 acc ----------------
// 128x128 tile, 4 waves, each wave 64x64 via 4x4 frags of mfma_f32_16x16x32_bf16.
// LDS row stride 72 (144B): 16B-aligned ds_read_b128, ~2-way banks (free).
template<int OUT_BF16>
__global__ __launch_bounds__(256) void gemm_bt(const unsigned short* __restrict__ A,
                                               const unsigned short* __restrict__ Bm,
                                               void* __restrict__ Cout,
                                               int Mdim, int Ndim, int Kdim)
{
  __shared__ unsigned short As[128*72];
  __shared__ unsigned short Bs[128*72];
  int tid = threadIdx.x, lane = tid & 63, w = tid >> 6, lr = lane & 15, lg = lane >> 4;
  int ntn = Ndim >> 7;
  long m0 = (long)(blockIdx.x / ntn) * 128;
  long n0 = (long)(blockIdx.x % ntn) * 128;
  int wr = (w >> 1) * 64, wc = (w & 1) * 64;
  f32x4 acc[4][4] = {};

  for (int k0 = 0; k0 < Kdim; k0 += 64){
    __syncthreads();
    #pragma unroll
    for (int i = 0; i < 4; ++i){
      int cc = tid + 256*i; int row = cc >> 3, ch = cc & 7;
      *(uint4*)&As[row*72 + ch*8] = *(const uint4*)&A[(m0+row)*Kdim + k0 + ch*8];
      *(uint4*)&Bs[row*72 + ch*8] = *(const uint4*)&Bm[(n0+row)*Kdim + k0 + ch*8];
    }
    __syncthreads();
    #pragma unroll
    for (int kk = 0; kk < 64; kk += 32){
      bf16x8 af[4], bfr[4];
      #pragma unroll
      for (int m = 0; m < 4; ++m) af[m]  = *(const bf16x8*)&As[(wr + m*16 + lr)*72 + kk + 8*lg];
      #pragma unroll
      for (int n = 0; n < 4; ++n) bfr[n] = *(const bf16x8*)&Bs[(wc + n*16 + lr)*72 + kk + 8*lg];
      #pragma unroll
      for (int m = 0; m < 4; ++m)
        #pragma unroll
        for (int n = 0; n < 4; ++n)
          acc[m][n] = __builtin_amdgcn_mfma_f32_16x16x32_bf16(af[m], bfr[n], acc[m][n], 0, 0, 0);
    }
  }
  // C/D layout: col = lane&15, row = 4*(lane>>4) + reg
  #pragma unroll
  for (int m = 0; m < 4; ++m)
    #pragma unroll
    for (int n = 0; n < 4; ++n)
      #pragma unroll
      for (int r = 0; r < 4; ++r){
        long row = m0 + wr + m*16 + 4*lg + r;
        long col = n0 + wc + n*16 + lr;
        float v = acc[m][n][r];
        if (OUT_BF16) ((unsigned short*)Cout)[row*Ndim + col] = f2bf(v);
        else          ((float*)Cout)[row*Ndim + col] = v;
      }
}

// ---------------- RoPE + transpose (B,S,Hx,64)->(B,Hx,S,64), bf16 ----------------
__global__ void rope_kernel(const unsigned short* __restrict__ in, const float* __restrict__ cosb,
                            const float* __restrict__ sinb, unsigned short* __restrict__ out,
                            int Hx, int dorope)
{
  int idx = blockIdx.x*256 + threadIdx.x;
  int total = gB*gS*Hx*4;
  if (idx >= total) return;
  int dq = idx & 3; int h = (idx >> 2) % Hx; int rem = idx / (4*Hx);
  int s = rem % gS; int b = rem / gS;
  int dp = dq*8;
  const unsigned short* ip = in + ((size_t)(b*gS+s)*Hx + h)*64;
  unsigned short xlo[8], xhi[8], olo[8], ohi[8];
  unpack8(*(const uint4*)(ip + dp), xlo);
  unpack8(*(const uint4*)(ip + dp + 32), xhi);
  if (dorope){
    const float* cp = cosb + (size_t)(b*gS+s)*64;
    const float* sp = sinb + (size_t)(b*gS+s)*64;
    #pragma unroll
    for (int u = 0; u < 8; ++u){
      float x1 = bf2f(xlo[u]), x2 = bf2f(xhi[u]);
      float c1 = cp[dp+u], s1 = sp[dp+u], c2 = cp[dp+32+u], s2 = sp[dp+32+u];
      olo[u] = f2bf(x1*c1 - x2*s1);
      ohi[u] = f2bf(x2*c2 + x1*s2);
    }
  } else {
    #pragma unroll
    for (int u = 0; u < 8; ++u){ olo[u] = xlo[u]; ohi[u] = xhi[u]; }
  }
  unsigned short* op = out + ((size_t)(b*Hx+h)*gS + s)*64;
  *(uint4*)(op + dp)      = pack8(olo);
  *(uint4*)(op + dp + 32) = pack8(ohi);
}

// ---------------- local sliding-window attention ----------------
// WG = (b, h, 64-query block). keys [q0-256, q0+64) in 10 tiles of 32.
// wave w owns 16 query rows. hybrid = 0.5*local_out, layout (B,S,H,64) f32.
__global__ __launch_bounds__(256) void local_attn(const unsigned short* __restrict__ q_r,
                                                  const unsigned short* __restrict__ k_r,
                                                  const unsigned short* __restrict__ v_tr,
                                                  float* __restrict__ hybrid)
{
  __shared__ unsigned short Qs[64*72];
  __shared__ unsigned short Ks[32*72];
  __shared__ unsigned short VTs[64*40];
  __shared__ unsigned short Ps[4*16*40];
  int bid = blockIdx.x;
  int qt = bid & 63; int h = (bid >> 6) & 31; int b = bid >> 11;
  int kvh = h >> 2;
  int q0 = qt*64;
  int tid = threadIdx.x, lane = tid & 63, w = tid >> 6, lr = lane & 15, lg = lane >> 4;
  const unsigned short* qp = q_r  + ((size_t)(b*gH  +h  )*gS)*64;
  const unsigned short* kp = k_r  + ((size_t)(b*gKVH+kvh)*gS)*64;
  const unsigned short* vp = v_tr + ((size_t)(b*gKVH+kvh)*gS)*64;

  #pragma unroll
  for (int i = 0; i < 2; ++i){
    int cc = tid + 256*i; int row = cc >> 3, ch = cc & 7;
    *(uint4*)&Qs[row*72 + ch*8] = *(const uint4*)&qp[(q0+row)*64 + ch*8];
  }
  float mrun[4], lsum[4];
  f32x4 accO[4] = {};
  #pragma unroll
  for (int r = 0; r < 4; ++r){ mrun[r] = -1e30f; lsum[r] = 0.f; }
  int wq = w*16;
  int kt0 = (q0 >= 256) ? 0 : ((256 - q0) >> 5);

  for (int kt = kt0; kt < 10; ++kt){
    int kb = q0 - 256 + kt*32;            // >= 0 guaranteed (q0, kt0 multiples)
    __syncthreads();
    {
      int row = tid >> 3, ch = tid & 7;
      *(uint4*)&Ks[row*72 + ch*8] = *(const uint4*)&kp[(kb+row)*64 + ch*8];
      unsigned short tv[8];
      unpack8(*(const uint4*)&vp[(kb+row)*64 + ch*8], tv);
      #pragma unroll
      for (int u = 0; u < 8; ++u) VTs[(ch*8+u)*40 + row] = tv[u];
    }
    __syncthreads();

    f32x4 sc[2] = {};
    #pragma unroll
    for (int kk = 0; kk < 64; kk += 32){
      bf16x8 aq = *(const bf16x8*)&Qs[(wq+lr)*72 + kk + 8*lg];
      #pragma unroll
      for (int f = 0; f < 2; ++f){
        bf16x8 bk = *(const bf16x8*)&Ks[(f*16+lr)*72 + kk + 8*lg];
        sc[f] = __builtin_amdgcn_mfma_f32_16x16x32_bf16(aq, bk, sc[f], 0, 0, 0);
      }
    }
    float rmax[4]; bool keepM[2][4];
    #pragma unroll
    for (int r = 0; r < 4; ++r) rmax[r] = -1e30f;
    #pragma unroll
    for (int f = 0; f < 2; ++f)
      #pragma unroll
      for (int r = 0; r < 4; ++r){
        int i = wq + 4*lg + r;            // local query row
        int j = kt*32 + f*16 + lr;        // window column
        bool keep = (j > i) && (j <= i + 256);
        keepM[f][r] = keep;
        float s = sc[f][r]*0.125f;
        s = keep ? s : -1e30f;
        sc[f][r] = s;
        rmax[r] = fmaxf(rmax[r], s);
      }
    #pragma unroll
    for (int off = 1; off < 16; off <<= 1)
      #pragma unroll
      for (int r = 0; r < 4; ++r) rmax[r] = fmaxf(rmax[r], __shfl_xor(rmax[r], off));
    float psum[4];
    #pragma unroll
    for (int r = 0; r < 4; ++r){
      float mn = fmaxf(mrun[r], rmax[r]);
      float al = __expf(mrun[r] - mn);
      mrun[r] = mn;
      lsum[r] *= al;
      #pragma unroll
      for (int dt = 0; dt < 4; ++dt) accO[dt][r] *= al;
      psum[r] = 0.f;
    }
    #pragma unroll
    for (int f = 0; f < 2; ++f)
      #pragma unroll
      for (int r = 0; r < 4; ++r){
        float p = keepM[f][r] ? __expf(sc[f][r] - mrun[r]) : 0.f;
        psum[r] += p;
        Ps[w*640 + (4*lg + r)*40 + f*16 + lr] = f2bf(p);
      }
    #pragma unroll
    for (int off = 1; off < 16; off <<= 1)
      #pragma unroll
      for (int r = 0; r < 4; ++r) psum[r] += __shfl_xor(psum[r], off);
    #pragma unroll
    for (int r = 0; r < 4; ++r) lsum[r] += psum[r];
    __syncthreads();
    bf16x8 ap = *(const bf16x8*)&Ps[w*640 + lr*40 + 8*lg];
    #pragma unroll
    for (int dt = 0; dt < 4; ++dt){
      bf16x8 bv = *(const bf16x8*)&VTs[(dt*16+lr)*40 + 8*lg];
      accO[dt] = __builtin_amdgcn_mfma_f32_16x16x32_bf16(ap, bv, accO[dt], 0, 0, 0);
    }
  }
  #pragma unroll
  for (int dt = 0; dt < 4; ++dt)
    #pragma unroll
    for (int r = 0; r < 4; ++r){
      int s = q0 + wq + 4*lg + r;
      int d = dt*16 + lr;
      float o = accO[dt][r] / lsum[r];
      hybrid[((size_t)(b*gS+s)*gH + h)*64 + d] = 0.5f * o;
    }
}

// ---------------- linear attention pass 1: per-chunk kv = pk^T v, ks = sum(pk) ----------------
__global__ __launch_bounds__(256) void lin_pass1(const unsigned short* __restrict__ k_r,
                                                 const unsigned short* __restrict__ v_tr,
                                                 float* __restrict__ kvbuf, float* __restrict__ ksbuf)
{
  __shared__ unsigned short pkT[64*136];
  __shared__ unsigned short vT[64*136];
  int bid = blockIdx.x;
  int c = bid & 31; int kvh = (bid >> 5) & 7; int b = bid >> 8;
  int tid = threadIdx.x, lane = tid & 63, w = tid >> 6, lr = lane & 15, lg = lane >> 4;
  int s0 = c*128;
  const unsigned short* kp = k_r  + ((size_t)(b*gKVH+kvh)*gS + s0)*64;
  const unsigned short* vp = v_tr + ((size_t)(b*gKVH+kvh)*gS + s0)*64;
  #pragma unroll
  for (int i = 0; i < 4; ++i){
    int cc = tid + 256*i; int key = cc >> 3, d0 = (cc & 7)*8;
    unsigned short t[8]; unpack8(*(const uint4*)(kp + key*64 + d0), t);
    #pragma unroll
    for (int u = 0; u < 8; ++u) pkT[(d0+u)*136 + key] = f2bf(phi_f(bf2f(t[u])));
    unsigned short tv[8]; unpack8(*(const uint4*)(vp + key*64 + d0), tv);
    #pragma unroll
    for (int u = 0; u < 8; ++u) vT[(d0+u)*136 + key] = tv[u];
  }
  __syncthreads();
  f32x4 acc[4] = {};
  #pragma unroll
  for (int kk = 0; kk < 128; kk += 32){
    bf16x8 a = *(const bf16x8*)&pkT[(16*w+lr)*136 + kk + 8*lg];
    #pragma unroll
    for (int et = 0; et < 4; ++et){
      bf16x8 bv = *(const bf16x8*)&vT[(16*et+lr)*136 + kk + 8*lg];
      acc[et] = __builtin_amdgcn_mfma_f32_16x16x32_bf16(a, bv, acc[et], 0, 0, 0);
    }
  }
  size_t base = (size_t)((b*gKVH+kvh)*gNC + c);
  float* kvp = kvbuf + base*4096;
  #pragma unroll
  for (int et = 0; et < 4; ++et)
    #pragma unroll
    for (int r = 0; r < 4; ++r)
      kvp[(16*w + 4*lg + r)*64 + 16*et + lr] = acc[et][r];
  if (tid < 64){
    float sum = 0.f;
    for (int k = 0; k < 128; ++k) sum += bf2f(pkT[tid*136 + k]);
    ksbuf[base*64 + tid] = sum;
  }
}

// ---------------- linear attention pass 2: in-place exclusive scan over chunks ----------------
__global__ void lin_pass2(float* __restrict__ kvbuf, float* __restrict__ ksbuf){
  int t = blockIdx.x*256 + threadIdx.x;
  const int per = 4096 + 64;
  if (t >= gB*gKVH*per) return;
  int bh = t / per; int e = t % per;
  if (e < 4096){
    float* p = kvbuf + (size_t)bh*gNC*4096 + e;
    float acc = 0.f;
    for (int cix = 0; cix < gNC; ++cix){ float v = p[(size_t)cix*4096]; p[(size_t)cix*4096] = acc; acc += v; }
  } else {
    float* p = ksbuf + (size_t)bh*gNC*64 + (e - 4096);
    float acc = 0.f;
    for (int cix = 0; cix < gNC; ++cix){ float v = p[cix*64]; p[cix*64] = acc; acc += v; }
  }
}

// ---------------- linear attention pass 3: intra + inter, hybrid += 0.5*out ----------------
__global__ __launch_bounds__(256) void lin_pass3(const unsigned short* __restrict__ q_r,
                                                 const unsigned short* __restrict__ k_r,
                                                 const unsigned short* __restrict__ v_tr,
                                                 const float* __restrict__ Sprev,
                                                 const float* __restrict__ zprev,
                                                 float* __restrict__ hybrid)
{
  __shared__ unsigned short pq[128*72];
  __shared__ unsigned short pk[64*72];
  __shared__ unsigned short Ph[128*72];
  __shared__ unsigned short vT[64*72];
  __shared__ unsigned short SpT[64*72];
  __shared__ float zp[64];

  int bid = blockIdx.x;
  int c = bid & 31; int h = (bid >> 5) & 31; int b = bid >> 10;
  int kvh = h >> 2;
  int tid = threadIdx.x, lane = tid & 63, w = tid >> 6, lr = lane & 15, lg = lane >> 4;
  int s0 = c*128;
  const unsigned short* qp = q_r  + ((size_t)(b*gH  +h  )*gS + s0)*64;
  const unsigned short* kp = k_r  + ((size_t)(b*gKVH+kvh)*gS + s0)*64;
  const unsigned short* vp = v_tr + ((size_t)(b*gKVH+kvh)*gS + s0)*64;
  const float* Sp  = Sprev + ((size_t)((b*gKVH+kvh)*gNC + c))*4096;
  const float* zpg = zprev + ((size_t)((b*gKVH+kvh)*gNC + c))*64;

  #pragma unroll
  for (int i = 0; i < 4; ++i){
    int cc = tid + 256*i; int row = cc >> 3, d0 = (cc & 7)*8;
    unsigned short t[8]; unpack8(*(const uint4*)(qp + row*64 + d0), t);
    #pragma unroll
    for (int u = 0; u < 8; ++u) pq[row*72 + d0 + u] = f2bf(phi_f(bf2f(t[u])));
  }
  #pragma unroll
  for (int i = 0; i < 16; ++i){
    int f = tid + 256*i; int d = f >> 6, e = f & 63;
    SpT[e*72 + d] = f2bf(Sp[f]);
  }
  if (tid < 64) zp[tid] = zpg[tid];

  float den[2][4] = {};
  f32x4 accO[2][4] = {};

  for (int kh = 0; kh < 2; ++kh){
    __syncthreads();
    #pragma unroll
    for (int i = 0; i < 2; ++i){
      int cc = tid + 256*i; int kr = cc >> 3, d0 = (cc & 7)*8;
      unsigned short t[8]; unpack8(*(const uint4*)(kp + (kh*64+kr)*64 + d0), t);
      #pragma unroll
      for (int u = 0; u < 8; ++u) pk[kr*72 + d0 + u] = f2bf(phi_f(bf2f(t[u])));
      unsigned short tv[8]; unpack8(*(const uint4*)(vp + (kh*64+kr)*64 + d0), tv);
      #pragma unroll
      for (int u = 0; u < 8; ++u) vT[(d0+u)*72 + kr] = tv[u];
    }
    __syncthreads();

    f32x4 sc[2][4] = {};
    #pragma unroll
    for (int kk = 0; kk < 64; kk += 32){
      bf16x8 a[2];
      #pragma unroll
      for (int rt = 0; rt < 2; ++rt) a[rt] = *(const bf16x8*)&pq[(32*w+16*rt+lr)*72 + kk + 8*lg];
      #pragma unroll
      for (int ct = 0; ct < 4; ++ct){
        bf16x8 bk = *(const bf16x8*)&pk[(16*ct+lr)*72 + kk + 8*lg];
        #pragma unroll
        for (int rt = 0; rt < 2; ++rt)
          sc[rt][ct] = __builtin_amdgcn_mfma_f32_16x16x32_bf16(a[rt], bk, sc[rt][ct], 0, 0, 0);
      }
    }
    #pragma unroll
    for (int rt = 0; rt < 2; ++rt)
      #pragma unroll
      for (int ct = 0; ct < 4; ++ct)
        #pragma unroll
        for (int r = 0; r < 4; ++r){
          int qrow = 32*w + 16*rt + 4*lg + r;
          int krow = kh*64 + 16*ct + lr;
          float sv = (krow <= qrow) ? sc[rt][ct][r] : 0.f;   // tril incl. diagonal
          den[rt][r] += sv;
          Ph[qrow*72 + 16*ct + lr] = f2bf(sv);
        }
    // PV over this key half (Ph rows are wave-private)
    #pragma unroll
    for (int kk = 0; kk < 64; kk += 32){
      bf16x8 ap[2];
      #pragma unroll
      for (int rt = 0; rt < 2; ++rt) ap[rt] = *(const bf16x8*)&Ph[(32*w+16*rt+lr)*72 + kk + 8*lg];
      #pragma unroll
      for (int et = 0; et < 4; ++et){
        bf16x8 bv = *(const bf16x8*)&vT[(16*et+lr)*72 + kk + 8*lg];
        #pragma unroll
        for (int rt = 0; rt < 2; ++rt)
          accO[rt][et] = __builtin_amdgcn_mfma_f32_16x16x32_bf16(ap[rt], bv, accO[rt][et], 0, 0, 0);
      }
    }
  }
  // inter-chunk: num += pq @ Sprev
  #pragma unroll
  for (int kk = 0; kk < 64; kk += 32){
    bf16x8 a[2];
    #pragma unroll
    for (int rt = 0; rt < 2; ++rt) a[rt] = *(const bf16x8*)&pq[(32*w+16*rt+lr)*72 + kk + 8*lg];
    #pragma unroll
    for (int et = 0; et < 4; ++et){
      bf16x8 bs = *(const bf16x8*)&SpT[(16*et+lr)*72 + kk + 8*lg];
      #pragma unroll
      for (int rt = 0; rt < 2; ++rt)
        accO[rt][et] = __builtin_amdgcn_mfma_f32_16x16x32_bf16(a[rt], bs, accO[rt][et], 0, 0, 0);
    }
  }
  // den += pq @ zprev (lane-partial over d-slice), then reduce over the 16-lane group
  #pragma unroll
  for (int rt = 0; rt < 2; ++rt)
    #pragma unroll
    for (int r = 0; r < 4; ++r){
      int qrow = 32*w + 16*rt + 4*lg + r;
      float part = 0.f;
      #pragma unroll
      for (int u = 0; u < 4; ++u){
        int d = 4*lr + u;
        part += bf2f(pq[qrow*72 + d]) * zp[d];
      }
      den[rt][r] += part;
      #pragma unroll
      for (int off = 1; off < 16; off <<= 1)
        den[rt][r] += __shfl_xor(den[rt][r], off);
    }
  #pragma unroll
  for (int rt = 0; rt < 2; ++rt)
    #pragma unroll
    for (int et = 0; et < 4; ++et)
      #pragma unroll
      for (int r = 0; r < 4; ++r){
        int qrow = 32*w + 16*rt + 4*lg + r;
        int e = 16*et + lr;
        float o = accO[rt][et][r] / (den[rt][r] + 1e-6f);
        int s = s0 + qrow;
        hybrid[((size_t)(b*gS+s)*gH + h)*64 + e] += 0.5f * o;
      }
}

// ---------------- host launch ----------------
extern "C" void kernel_launch(void* const* d_in, const int* in_sizes, int n_in,
                              void* d_out, int out_size, void* d_ws, size_t ws_size,
                              hipStream_t stream)
{
  const float* hidden = (const float*)d_in[0];
  const float* cosb   = (const float*)d_in[1];
  const float* sinb   = (const float*)d_in[2];
  const float* Wq     = (const float*)d_in[3];
  const float* Wk     = (const float*)d_in[4];
  const float* Wv     = (const float*)d_in[5];
  const float* Wo     = (const float*)d_in[6];
  float* out = (float*)d_out;

  char* ws = (char*)d_ws;
  size_t off = 0;
  auto alloc = [&](size_t bytes)->void*{
    void* p = ws + off; off += (bytes + 255) & ~(size_t)255; return p;
  };
  unsigned short* hbf   = (unsigned short*)alloc((size_t)gBS*gHID*2);  // hidden bf16; reused as hybrid bf16
  unsigned short* wqb   = (unsigned short*)alloc((size_t)gHID*gHID*2);
  unsigned short* wkb   = (unsigned short*)alloc((size_t)512*gHID*2);
  unsigned short* wvb   = (unsigned short*)alloc((size_t)512*gHID*2);
  unsigned short* wob   = (unsigned short*)alloc((size_t)gHID*gHID*2);
  unsigned short* qproj = (unsigned short*)alloc((size_t)gBS*gHID*2);  // (B,S,H,64)
  unsigned short* kproj = (unsigned short*)alloc((size_t)gBS*512*2);   // (B,S,KVH,64)
  unsigned short* vproj = (unsigned short*)alloc((size_t)gBS*512*2);
  unsigned short* q_r   = (unsigned short*)alloc((size_t)gBS*gHID*2);  // (B,H,S,64)
  unsigned short* k_r   = (unsigned short*)alloc((size_t)gBS*512*2);   // (B,KVH,S,64)
  unsigned short* v_tr  = (unsigned short*)alloc((size_t)gBS*512*2);
  float* hybrid         = (float*)alloc((size_t)gBS*gHID*4);           // (B,S,H,64)
  float* kvbuf          = (float*)alloc((size_t)gB*gKVH*gNC*4096*4);   // -> Sprev after scan
  float* ksbuf          = (float*)alloc((size_t)gB*gKVH*gNC*64*4);     // -> zprev after scan

  auto cvt = [&](const float* in, unsigned short* o, int n){
    int nb = (n/4 + 255)/256; if (nb > 4096) nb = 4096;
    cvt_kernel<<<dim3(nb), dim3(256), 0, stream>>>(in, o, n);
  };
  cvt(hidden, hbf, gBS*gHID);
  cvt(Wq, wqb, gHID*gHID);
  cvt(Wk, wkb, 512*gHID);
  cvt(Wv, wvb, 512*gHID);
  cvt(Wo, wob, gHID*gHID);

  gemm_bt<1><<<dim3(64*16), dim3(256), 0, stream>>>(hbf, wqb, (void*)qproj, 8192, 2048, 2048);
  gemm_bt<1><<<dim3(64*4),  dim3(256), 0, stream>>>(hbf, wkb, (void*)kproj, 8192, 512, 2048);
  gemm_bt<1><<<dim3(64*4),  dim3(256), 0, stream>>>(hbf, wvb, (void*)vproj, 8192, 512, 2048);

  rope_kernel<<<dim3((gB*gS*gH*4)/256),   dim3(256), 0, stream>>>(qproj, cosb, sinb, q_r, gH, 1);
  rope_kernel<<<dim3((gB*gS*gKVH*4)/256), dim3(256), 0, stream>>>(kproj, cosb, sinb, k_r, gKVH, 1);
  rope_kernel<<<dim3((gB*gS*gKVH*4)/256), dim3(256), 0, stream>>>(vproj, cosb, sinb, v_tr, gKVH, 0);

  local_attn<<<dim3(gB*gH*64), dim3(256), 0, stream>>>(q_r, k_r, v_tr, hybrid);
  lin_pass1<<<dim3(gB*gKVH*gNC), dim3(256), 0, stream>>>(k_r, v_tr, kvbuf, ksbuf);
  lin_pass2<<<dim3((gB*gKVH*(4096+64) + 255)/256), dim3(256), 0, stream>>>(kvbuf, ksbuf);
  lin_pass3<<<dim3(gB*gH*gNC), dim3(256), 0, stream>>>(q_r, k_r, v_tr, kvbuf, ksbuf, hybrid);

  cvt(hybrid, hbf, gBS*gHID);
  gemm_bt<0><<<dim3(64*16), dim3(256), 0, stream>>>(hbf, wob, (void*)out, 8192, 2048, 2048);
}

// Round 2
// 482.129 us; speedup vs baseline: 1.1026x; 1.1026x over previous
//
#include <hip/hip_runtime.h>

// ---------------- problem constants ----------------
#define gB 2
#define gS 4096
#define gH 32
#define gKVH 8
#define gHID 2048
#define gNC 32            // S / CHK
#define gBS (gB*gS)       // 8192
// D = 64, WIN = 256, CHK = 128, NREP = 4 are hard-coded below.

using bf16x8 = __attribute__((ext_vector_type(8))) short;
using f32x4  = __attribute__((ext_vector_type(4))) float;

__device__ __forceinline__ float bf2f(unsigned short u){
  return __uint_as_float(((unsigned)u) << 16);
}
__device__ __forceinline__ unsigned short f2bf(float f){
  unsigned u = __float_as_uint(f);
  u = (u + 0x7fffu + ((u >> 16) & 1u)) >> 16;   // RNE
  return (unsigned short)u;
}
__device__ __forceinline__ float phi_f(float x){ return x > 0.f ? x + 1.f : __expf(x); } // elu(x)+1

__device__ __forceinline__ void unpack8(uint4 v, unsigned short* o){
  o[0]=(unsigned short)(v.x&0xffffu); o[1]=(unsigned short)(v.x>>16);
  o[2]=(unsigned short)(v.y&0xffffu); o[3]=(unsigned short)(v.y>>16);
  o[4]=(unsigned short)(v.z&0xffffu); o[5]=(unsigned short)(v.z>>16);
  o[6]=(unsigned short)(v.w&0xffffu); o[7]=(unsigned short)(v.w>>16);
}
__device__ __forceinline__ uint4 pack8(const unsigned short* s){
  uint4 v;
  v.x = (unsigned)s[0] | ((unsigned)s[1]<<16);
  v.y = (unsigned)s[2] | ((unsigned)s[3]<<16);
  v.z = (unsigned)s[4] | ((unsigned)s[5]<<16);
  v.w = (unsigned)s[6] | ((unsigned)s[7]<<16);
  return v;
}

// async global->LDS, 16B per lane; LDS dest = wave-uniform base + lane*16
typedef const __attribute__((address_space(1))) void* gas_ptr;
typedef __attribute__((address_space(3))) void* las_ptr;
__device__ __forceinline__ void gload16(const void* g, void* l){
  __builtin_amdgcn_global_load_lds((gas_ptr)g, (las_ptr)l, 16, 0, 0);
}

// ---------------- f32 -> bf16 convert ----------------
__global__ void cvt_kernel(const float* __restrict__ in, unsigned short* __restrict__ out, int n){
  int stride = gridDim.x * blockDim.x;
  for (int i = blockIdx.x*blockDim.x + threadIdx.x; i*4 < n; i += stride){
    float4 v = *(const float4*)(in + (size_t)i*4);
    ushort4 o;
    o.x = f2bf(v.x); o.y = f2bf(v.y); o.z = f2bf(v.z); o.w = f2bf(v.w);
    *(ushort4*)(out + (size_t)i*4) = o;
  }
}

// ---------------- combine two bf16 buffers (a+b) -> bf16 ----------------
__global__ void combine_kernel(const unsigned short* __restrict__ a,
                               const unsigned short* __restrict__ b,
                               unsigned short* __restrict__ o, int n8){
  int i = blockIdx.x*256 + threadIdx.x;
  if (i >= n8) return;
  uint4 va = ((const uint4*)a)[i], vb = ((const uint4*)b)[i];
  unsigned short ta[8], tb[8], to[8];
  unpack8(va, ta); unpack8(vb, tb);
  #pragma unroll
  for (int u = 0; u < 8; ++u) to[u] = f2bf(bf2f(ta[u]) + bf2f(tb[u]));
  ((uint4*)o)[i] = pack8(to);
}

// ---------------- GEMM: C[M,N] = A[M,K] * B[N,K]^T, bf16 in, f32 acc ----------------
// m97 structure: 128x128 tile, BK=64, 4 waves, 4x4 frags, global_load_lds 16B
// staging into LINEAR [128][64] LDS (layout forced by gload_lds lane ordering).
template<int OUT_BF16>
__global__ __launch_bounds__(256) void gemm_bt(const unsigned short* __restrict__ A,
                                               const unsigned short* __restrict__ Bm,
                                               void* __restrict__ Cout,
                                               int Mdim, int Ndim, int Kdim)
{
  __shared__ unsigned short As[128*64];
  __shared__ unsigned short Bs[128*64];
  int tid = threadIdx.x, lane = tid & 63, w = tid >> 6, lr = lane & 15, lg = lane >> 4;
  int ntn = Ndim >> 7;
  long m0 = (long)(blockIdx.x / ntn) * 128;
  long n0 = (long)(blockIdx.x % ntn) * 128;
  int wr = (w >> 1) * 64, wc = (w & 1) * 64;
  int srow = lane >> 3, scol = (lane & 7) * 8;   // within an 8-row chunk
  f32x4 acc[4][4] = {};

  for (int k0 = 0; k0 < Kdim; k0 += 64){
    __syncthreads();
    #pragma unroll
    for (int i = 0; i < 4; ++i){
      int c = w*4 + i;                 // chunk 0..15, wave-uniform
      int row = c*8 + srow;
      gload16(&A[(m0+row)*Kdim + k0 + scol], &As[c*512]);
      gload16(&Bm[(n0+row)*Kdim + k0 + scol], &Bs[c*512]);
    }
    __syncthreads();                   // drains vmcnt(0) -> staged data visible
    #pragma unroll
    for (int kk = 0; kk < 64; kk += 32){
      bf16x8 af[4], bfr[4];
      #pragma unroll
      for (int m = 0; m < 4; ++m) af[m]  = *(const bf16x8*)&As[(wr + m*16 + lr)*64 + kk + 8*lg];
      #pragma unroll
      for (int n = 0; n < 4; ++n) bfr[n] = *(const bf16x8*)&Bs[(wc + n*16 + lr)*64 + kk + 8*lg];
      #pragma unroll
      for (int m = 0; m < 4; ++m)
        #pragma unroll
        for (int n = 0; n < 4; ++n)
          acc[m][n] = __builtin_amdgcn_mfma_f32_16x16x32_bf16(af[m], bfr[n], acc[m][n], 0, 0, 0);
    }
  }
  // C/D layout: col = lane&15, row = 4*(lane>>4) + reg
  #pragma unroll
  for (int m = 0; m < 4; ++m)
    #pragma unroll
    for (int n = 0; n < 4; ++n)
      #pragma unroll
      for (int r = 0; r < 4; ++r){
        long row = m0 + wr + m*16 + 4*lg + r;
        long col = n0 + wc + n*16 + lr;
        float v = acc[m][n][r];
        if (OUT_BF16) ((unsigned short*)Cout)[row*Ndim + col] = f2bf(v);
        else          ((float*)Cout)[row*Ndim + col] = v;
      }
}

// ---------------- RoPE + transpose (B,S,tokstride/64...) -> (B,Hx,S,64), bf16 ----------------
__global__ void rope_kernel(const unsigned short* __restrict__ in, const float* __restrict__ cosb,
                            const float* __restrict__ sinb, unsigned short* __restrict__ out,
                            int Hx, int tokstride)
{
  int idx = blockIdx.x*256 + threadIdx.x;
  int total = gB*gS*Hx*4;
  if (idx >= total) return;
  int dq = idx & 3; int h = (idx >> 2) % Hx; int rem = idx / (4*Hx);
  int s = rem % gS; int b = rem / gS;
  int dp = dq*8;
  const unsigned short* ip = in + (size_t)(b*gS+s)*tokstride + h*64;
  unsigned short xlo[8], xhi[8], olo[8], ohi[8];
  unpack8(*(const uint4*)(ip + dp), xlo);
  unpack8(*(const uint4*)(ip + dp + 32), xhi);
  const float* cp = cosb + (size_t)(b*gS+s)*64;
  const float* sp = sinb + (size_t)(b*gS+s)*64;
  #pragma unroll
  for (int u = 0; u < 8; ++u){
    float x1 = bf2f(xlo[u]), x2 = bf2f(xhi[u]);
    float c1 = cp[dp+u], s1 = sp[dp+u], c2 = cp[dp+32+u], s2 = sp[dp+32+u];
    olo[u] = f2bf(x1*c1 - x2*s1);
    ohi[u] = f2bf(x2*c2 + x1*s2);
  }
  unsigned short* op = out + ((size_t)(b*Hx+h)*gS + s)*64;
  *(uint4*)(op + dp)      = pack8(olo);
  *(uint4*)(op + dp + 32) = pack8(ohi);
}

// ---------------- 64x64 tile transpose -> d-major (B,KVH,64,S) ----------------
// mode 0: in = (B,KVH,S,64) rows (k_r).  mode 1: in = kvproj (B,S,1024), v part at +512.
__global__ __launch_bounds__(256) void transpose64(const unsigned short* __restrict__ in,
                                                   unsigned short* __restrict__ out,
                                                   int tokStride, int mode)
{
  __shared__ unsigned short T[64*72];
  int bid = blockIdx.x;
  int st = bid & 63; int kvh = (bid >> 6) & 7; int b = bid >> 9;
  int s0 = st*64;
  int tid = threadIdx.x;
  const unsigned short* ip;
  size_t tokstr;
  if (mode == 0){ ip = in + ((size_t)(b*gKVH+kvh)*gS + s0)*64;                tokstr = 64; }
  else          { ip = in + (size_t)(b*gS+s0)*tokStride + 512 + kvh*64;       tokstr = tokStride; }
  #pragma unroll
  for (int i = 0; i < 2; ++i){
    int cc = tid + 256*i; int sl = cc >> 3, ch = cc & 7;
    *(uint4*)&T[sl*72 + ch*8] = *(const uint4*)&ip[(size_t)sl*tokstr + ch*8];
  }
  __syncthreads();
  unsigned short* op = out + ((size_t)(b*gKVH+kvh)*64)*gS;
  #pragma unroll
  for (int i = 0; i < 2; ++i){
    int cc = tid + 256*i; int d = cc >> 3, ch = cc & 7;
    unsigned short t[8];
    #pragma unroll
    for (int u = 0; u < 8; ++u) t[u] = T[(ch*8+u)*72 + d];
    *(uint4*)&op[(size_t)d*gS + s0 + ch*8] = pack8(t);
  }
}

// ---------------- local sliding-window attention ----------------
// WG = (b, h, 64-query block). keys [q0-256, q0+64) in 5 tiles of 64.
// wave w owns 16 query rows. writes 0.5*out as bf16 (B,S,H,64).
__global__ __launch_bounds__(256) void local_attn(const unsigned short* __restrict__ q_r,
                                                  const unsigned short* __restrict__ k_r,
                                                  const unsigned short* __restrict__ vt,
                                                  unsigned short* __restrict__ olocal)
{
  __shared__ unsigned short Qs[64*72];
  __shared__ unsigned short Ks[64*72];
  __shared__ unsigned short VTs[64*72];
  __shared__ unsigned short Ps[4*16*72];
  int bid = blockIdx.x;
  int qt = bid & 63; int h = (bid >> 6) & 31; int b = bid >> 11;
  int kvh = h >> 2;
  int q0 = qt*64;
  int tid = threadIdx.x, lane = tid & 63, w = tid >> 6, lr = lane & 15, lg = lane >> 4;
  const unsigned short* qp = q_r + ((size_t)(b*gH  +h  )*gS + q0)*64;
  const unsigned short* kp = k_r + ((size_t)(b*gKVH+kvh)*gS)*64;
  const unsigned short* vp = vt  + ((size_t)(b*gKVH+kvh)*64)*gS;   // rows d, stride S

  #pragma unroll
  for (int i = 0; i < 2; ++i){
    int cc = tid + 256*i; int row = cc >> 3, ch = cc & 7;
    *(uint4*)&Qs[row*72 + ch*8] = *(const uint4*)&qp[row*64 + ch*8];
  }
  float mrun[4], lsum[4];
  f32x4 accO[4] = {};
  #pragma unroll
  for (int r = 0; r < 4; ++r){ mrun[r] = -1e30f; lsum[r] = 0.f; }
  int wq = w*16;
  int kt0 = (q0 >= 256) ? 0 : ((256 - q0) >> 6);

  for (int kt = kt0; kt < 5; ++kt){
    int kb = q0 - 256 + kt*64;            // >= 0 guaranteed
    __syncthreads();
    #pragma unroll
    for (int i = 0; i < 2; ++i){
      int cc = tid + 256*i; int row = cc >> 3, ch = cc & 7;
      *(uint4*)&Ks[row*72 + ch*8]  = *(const uint4*)&kp[(size_t)(kb+row)*64 + ch*8];
      *(uint4*)&VTs[row*72 + ch*8] = *(const uint4*)&vp[(size_t)row*gS + kb + ch*8];
    }
    __syncthreads();

    f32x4 sc[4] = {};
    #pragma unroll
    for (int kk = 0; kk < 64; kk += 32){
      bf16x8 aq = *(const bf16x8*)&Qs[(wq+lr)*72 + kk + 8*lg];
      #pragma unroll
      for (int f = 0; f < 4; ++f){
        bf16x8 bk = *(const bf16x8*)&Ks[(f*16+lr)*72 + kk + 8*lg];
        sc[f] = __builtin_amdgcn_mfma_f32_16x16x32_bf16(aq, bk, sc[f], 0, 0, 0);
      }
    }
    float rmax[4]; bool keepM[4][4];
    #pragma unroll
    for (int r = 0; r < 4; ++r) rmax[r] = -1e30f;
    #pragma unroll
    for (int f = 0; f < 4; ++f)
      #pragma unroll
      for (int r = 0; r < 4; ++r){
        int i = wq + 4*lg + r;            // local query row
        int j = kt*64 + f*16 + lr;        // window column (0..319)
        bool keep = (j > i) && (j <= i + 256);
        keepM[f][r] = keep;
        float s = sc[f][r]*0.125f;
        s = keep ? s : -1e30f;
        sc[f][r] = s;
        rmax[r] = fmaxf(rmax[r], s);
      }
    #pragma unroll
    for (int off = 1; off < 16; off <<= 1)
      #pragma unroll
      for (int r = 0; r < 4; ++r) rmax[r] = fmaxf(rmax[r], __shfl_xor(rmax[r], off));
    float psum[4];
    #pragma unroll
    for (int r = 0; r < 4; ++r){
      float mn = fmaxf(mrun[r], rmax[r]);
      float al = __expf(mrun[r] - mn);
      mrun[r] = mn;
      lsum[r] *= al;
      #pragma unroll
      for (int dt = 0; dt < 4; ++dt) accO[dt][r] *= al;
      psum[r] = 0.f;
    }
    #pragma unroll
    for (int f = 0; f < 4; ++f)
      #pragma unroll
      for (int r = 0; r < 4; ++r){
        float p = keepM[f][r] ? __expf(sc[f][r] - mrun[r]) : 0.f;
        psum[r] += p;
        Ps[w*1152 + (4*lg + r)*72 + f*16 + lr] = f2bf(p);
      }
    #pragma unroll
    for (int off = 1; off < 16; off <<= 1)
      #pragma unroll
      for (int r = 0; r < 4; ++r) psum[r] += __shfl_xor(psum[r], off);
    #pragma unroll
    for (int r = 0; r < 4; ++r) lsum[r] += psum[r];
    // Ps write->read is same-wave LDS (in-order DS pipe) — no barrier needed.
    #pragma unroll
    for (int kk = 0; kk < 64; kk += 32){
      bf16x8 ap = *(const bf16x8*)&Ps[w*1152 + lr*72 + kk + 8*lg];
      #pragma unroll
      for (int dt = 0; dt < 4; ++dt){
        bf16x8 bv = *(const bf16x8*)&VTs[(dt*16+lr)*72 + kk + 8*lg];
        accO[dt] = __builtin_amdgcn_mfma_f32_16x16x32_bf16(ap, bv, accO[dt], 0, 0, 0);
      }
    }
  }
  #pragma unroll
  for (int dt = 0; dt < 4; ++dt)
    #pragma unroll
    for (int r = 0; r < 4; ++r){
      int s = q0 + wq + 4*lg + r;
      int d = dt*16 + lr;
      float o = accO[dt][r] / lsum[r];
      olocal[((size_t)(b*gS+s)*gH + h)*64 + d] = f2bf(0.5f * o);
    }
}

// ---------------- linear attention pass 1: per-chunk kv = pk^T v, ks = sum(pk) ----------------
// ktr/vt are d-major (B,KVH,64,S). kv written d-major.
__global__ __launch_bounds__(256) void lin_pass1(const unsigned short* __restrict__ ktr,
                                                 const unsigned short* __restrict__ vt,
                                                 float* __restrict__ kvbuf, float* __restrict__ ksbuf)
{
  __shared__ unsigned short pkT[64*136];
  __shared__ unsigned short vT[64*136];
  int bid = blockIdx.x;
  int c = bid & 31; int kvh = (bid >> 5) & 7; int b = bid >> 8;
  int tid = threadIdx.x, lane = tid & 63, w = tid >> 6, lr = lane & 15, lg = lane >> 4;
  int s0 = c*128;
  const unsigned short* kp = ktr + ((size_t)(b*gKVH+kvh)*64)*gS;
  const unsigned short* vp = vt  + ((size_t)(b*gKVH+kvh)*64)*gS;
  #pragma unroll
  for (int i = 0; i < 4; ++i){
    int cc = tid + 256*i; int d = cc >> 4, ch = cc & 15;
    unsigned short t[8]; unpack8(*(const uint4*)&kp[(size_t)d*gS + s0 + ch*8], t);
    #pragma unroll
    for (int u = 0; u < 8; ++u) t[u] = f2bf(phi_f(bf2f(t[u])));
    *(uint4*)&pkT[d*136 + ch*8] = pack8(t);
    *(uint4*)&vT[d*136 + ch*8]  = *(const uint4*)&vp[(size_t)d*gS + s0 + ch*8];
  }
  __syncthreads();
  f32x4 acc[4] = {};
  #pragma unroll
  for (int kk = 0; kk < 128; kk += 32){
    bf16x8 a = *(const bf16x8*)&pkT[(16*w+lr)*136 + kk + 8*lg];
    #pragma unroll
    for (int et = 0; et < 4; ++et){
      bf16x8 bv = *(const bf16x8*)&vT[(16*et+lr)*136 + kk + 8*lg];
      acc[et] = __builtin_amdgcn_mfma_f32_16x16x32_bf16(a, bv, acc[et], 0, 0, 0);
    }
  }
  size_t base = (size_t)((b*gKVH+kvh)*gNC + c);
  float* kvp = kvbuf + base*4096;
  #pragma unroll
  for (int et = 0; et < 4; ++et)
    #pragma unroll
    for (int r = 0; r < 4; ++r)
      kvp[(16*w + 4*lg + r)*64 + 16*et + lr] = acc[et][r];   // d-major [d][e]
  if (tid < 64){
    float sum = 0.f;
    for (int k = 0; k < 128; ++k) sum += bf2f(pkT[tid*136 + k]);
    ksbuf[base*64 + tid] = sum;
  }
}

// ---------------- linear attention pass 2: exclusive scan; kv output TRANSPOSED to e-major ----------------
__global__ void lin_pass2(const float* __restrict__ kvin, float* __restrict__ kvout,
                          float* __restrict__ ksbuf){
  int t = blockIdx.x*256 + threadIdx.x;
  const int per = 4096 + 64;
  if (t >= gB*gKVH*per) return;
  int bh = t / per; int e = t % per;
  if (e < 4096){
    int d = e >> 6, ecol = e & 63;
    const float* p = kvin  + (size_t)bh*gNC*4096 + e;
    float* q       = kvout + (size_t)bh*gNC*4096 + ecol*64 + d;
    float acc = 0.f;
    for (int cix = 0; cix < gNC; ++cix){ float v = p[(size_t)cix*4096]; q[(size_t)cix*4096] = acc; acc += v; }
  } else {
    float* p = ksbuf + (size_t)bh*gNC*64 + (e - 4096);
    float acc = 0.f;
    for (int cix = 0; cix < gNC; ++cix){ float v = p[cix*64]; p[cix*64] = acc; acc += v; }
  }
}

// ---------------- linear attention pass 3: intra + inter, writes 0.5*out bf16 ----------------
__global__ __launch_bounds__(256) void lin_pass3(const unsigned short* __restrict__ q_r,
                                                 const unsigned short* __restrict__ k_r,
                                                 const unsigned short* __restrict__ vt,
                                                 const float* __restrict__ SprevT,   // e-major [e][d]
                                                 const float* __restrict__ zprev,
                                                 unsigned short* __restrict__ olin)
{
  __shared__ unsigned short pq[128*72];
  __shared__ unsigned short pk[64*72];
  __shared__ unsigned short Ph[128*72];
  __shared__ unsigned short vT[64*72];
  __shared__ unsigned short SpT[64*72];
  __shared__ float zp[64];

  int bid = blockIdx.x;
  int c = bid & 31; int h = (bid >> 5) & 31; int b = bid >> 10;
  int kvh = h >> 2;
  int tid = threadIdx.x, lane = tid & 63, w = tid >> 6, lr = lane & 15, lg = lane >> 4;
  int s0 = c*128;
  const unsigned short* qp = q_r + ((size_t)(b*gH  +h  )*gS + s0)*64;
  const unsigned short* kp = k_r + ((size_t)(b*gKVH+kvh)*gS + s0)*64;
  const unsigned short* vp = vt  + ((size_t)(b*gKVH+kvh)*64)*gS;
  const float* Sp  = SprevT + ((size_t)((b*gKVH+kvh)*gNC + c))*4096;
  const float* zpg = zprev  + ((size_t)((b*gKVH+kvh)*gNC + c))*64;

  #pragma unroll
  for (int i = 0; i < 4; ++i){
    int cc = tid + 256*i; int row = cc >> 3, d0 = (cc & 7)*8;
    unsigned short t[8]; unpack8(*(const uint4*)(qp + row*64 + d0), t);
    #pragma unroll
    for (int u = 0; u < 8; ++u) pq[row*72 + d0 + u] = f2bf(phi_f(bf2f(t[u])));
  }
  #pragma unroll
  for (int i = 0; i < 16; ++i){
    int f = tid + 256*i; int e = f >> 6, d = f & 63;
    SpT[e*72 + d] = f2bf(Sp[f]);           // Sp is e-major; consecutive lanes -> consecutive d
  }
  if (tid < 64) zp[tid] = zpg[tid];

  float den[2][4] = {};
  f32x4 accO[2][4] = {};

  for (int kh = 0; kh < 2; ++kh){
    __syncthreads();
    #pragma unroll
    for (int i = 0; i < 2; ++i){
      int cc = tid + 256*i; int kr = cc >> 3, d0 = (cc & 7)*8;
      unsigned short t[8]; unpack8(*(const uint4*)(kp + (kh*64+kr)*64 + d0), t);
      #pragma unroll
      for (int u = 0; u < 8; ++u) pk[kr*72 + d0 + u] = f2bf(phi_f(bf2f(t[u])));
      // vT rows e from d-major vt: e=kr, key cols d0..d0+7 within this half
      *(uint4*)&vT[kr*72 + d0] = *(const uint4*)&vp[(size_t)kr*gS + s0 + kh*64 + d0];
    }
    __syncthreads();

    f32x4 sc[2][4] = {};
    #pragma unroll
    for (int kk = 0; kk < 64; kk += 32){
      bf16x8 a[2];
      #pragma unroll
      for (int rt = 0; rt < 2; ++rt) a[rt] = *(const bf16x8*)&pq[(32*w+16*rt+lr)*72 + kk + 8*lg];
      #pragma unroll
      for (int ct = 0; ct < 4; ++ct){
        bf16x8 bk = *(const bf16x8*)&pk[(16*ct+lr)*72 + kk + 8*lg];
        #pragma unroll
        for (int rt = 0; rt < 2; ++rt)
          sc[rt][ct] = __builtin_amdgcn_mfma_f32_16x16x32_bf16(a[rt], bk, sc[rt][ct], 0, 0, 0);
      }
    }
    #pragma unroll
    for (int rt = 0; rt < 2; ++rt)
      #pragma unroll
      for (int ct = 0; ct < 4; ++ct)
        #pragma unroll
        for (int r = 0; r < 4; ++r){
          int qrow = 32*w + 16*rt + 4*lg + r;
          int krow = kh*64 + 16*ct + lr;
          float sv = (krow <= qrow) ? sc[rt][ct][r] : 0.f;   // tril incl. diagonal
          den[rt][r] += sv;
          Ph[qrow*72 + 16*ct + lr] = f2bf(sv);
        }
    // PV over this key half (Ph rows are wave-private; same-wave DS is in-order)
    #pragma unroll
    for (int kk = 0; kk < 64; kk += 32){
      bf16x8 ap[2];
      #pragma unroll
      for (int rt = 0; rt < 2; ++rt) ap[rt] = *(const bf16x8*)&Ph[(32*w+16*rt+lr)*72 + kk + 8*lg];
      #pragma unroll
      for (int et = 0; et < 4; ++et){
        bf16x8 bv = *(const bf16x8*)&vT[(16*et+lr)*72 + kk + 8*lg];
        #pragma unroll
        for (int rt = 0; rt < 2; ++rt)
          accO[rt][et] = __builtin_amdgcn_mfma_f32_16x16x32_bf16(ap[rt], bv, accO[rt][et], 0, 0, 0);
      }
    }
  }
  // inter-chunk: num += pq @ Sprev
  #pragma unroll
  for (int kk = 0; kk < 64; kk += 32){
    bf16x8 a[2];
    #pragma unroll
    for (int rt = 0; rt < 2; ++rt) a[rt] = *(const bf16x8*)&pq[(32*w+16*rt+lr)*72 + kk + 8*lg];
    #pragma unroll
    for (int et = 0; et < 4; ++et){
      bf16x8 bs = *(const bf16x8*)&SpT[(16*et+lr)*72 + kk + 8*lg];
      #pragma unroll
      for (int rt = 0; rt < 2; ++rt)
        accO[rt][et] = __builtin_amdgcn_mfma_f32_16x16x32_bf16(a[rt], bs, accO[rt][et], 0, 0, 0);
    }
  }
  // den += pq @ zprev, then 16-lane reduce
  #pragma unroll
  for (int rt = 0; rt < 2; ++rt)
    #pragma unroll
    for (int r = 0; r < 4; ++r){
      int qrow = 32*w + 16*rt + 4*lg + r;
      float part = 0.f;
      #pragma unroll
      for (int u = 0; u < 4; ++u){
        int d = 4*lr + u;
        part += bf2f(pq[qrow*72 + d]) * zp[d];
      }
      den[rt][r] += part;
      #pragma unroll
      for (int off = 1; off < 16; off <<= 1)
        den[rt][r] += __shfl_xor(den[rt][r], off);
    }
  #pragma unroll
  for (int rt = 0; rt < 2; ++rt)
    #pragma unroll
    for (int et = 0; et < 4; ++et)
      #pragma unroll
      for (int r = 0; r < 4; ++r){
        int qrow = 32*w + 16*rt + 4*lg + r;
        int e = 16*et + lr;
        float o = accO[rt][et][r] / (den[rt][r] + 1e-6f);
        int s = s0 + qrow;
        olin[((size_t)(b*gS+s)*gH + h)*64 + e] = f2bf(0.5f * o);
      }
}

// ---------------- host launch ----------------
extern "C" void kernel_launch(void* const* d_in, const int* in_sizes, int n_in,
                              void* d_out, int out_size, void* d_ws, size_t ws_size,
                              hipStream_t stream)
{
  const float* hidden = (const float*)d_in[0];
  const float* cosb   = (const float*)d_in[1];
  const float* sinb   = (const float*)d_in[2];
  const float* Wq     = (const float*)d_in[3];
  const float* Wk     = (const float*)d_in[4];
  const float* Wv     = (const float*)d_in[5];
  const float* Wo     = (const float*)d_in[6];
  float* out = (float*)d_out;

  char* ws = (char*)d_ws;
  size_t off = 0;
  auto alloc = [&](size_t bytes)->void*{
    void* p = ws + off; off += (bytes + 255) & ~(size_t)255; return p;
  };
  unsigned short* hbf    = (unsigned short*)alloc((size_t)gBS*gHID*2);  // hidden bf16; reused as hybrid bf16
  unsigned short* wqb    = (unsigned short*)alloc((size_t)gHID*gHID*2);
  unsigned short* wkvb   = (unsigned short*)alloc((size_t)1024*gHID*2); // [Wk;Wv]
  unsigned short* wob    = (unsigned short*)alloc((size_t)gHID*gHID*2);
  unsigned short* qproj  = (unsigned short*)alloc((size_t)gBS*gHID*2);  // (B,S,H,64)
  unsigned short* kvproj = (unsigned short*)alloc((size_t)gBS*1024*2);  // (B,S,[k|v])
  unsigned short* q_r    = (unsigned short*)alloc((size_t)gBS*gHID*2);  // (B,H,S,64)
  unsigned short* k_r    = (unsigned short*)alloc((size_t)gBS*512*2);   // (B,KVH,S,64)
  unsigned short* ktr    = (unsigned short*)alloc((size_t)gBS*512*2);   // (B,KVH,64,S)
  unsigned short* vt     = (unsigned short*)alloc((size_t)gBS*512*2);   // (B,KVH,64,S)
  unsigned short* olocal = (unsigned short*)alloc((size_t)gBS*gHID*2);  // bf16 0.5*local
  unsigned short* olin   = (unsigned short*)alloc((size_t)gBS*gHID*2);  // bf16 0.5*linear
  float* kvbuf           = (float*)alloc((size_t)gB*gKVH*gNC*4096*4);   // d-major per chunk
  float* kvT             = (float*)alloc((size_t)gB*gKVH*gNC*4096*4);   // e-major Sprev
  float* ksbuf           = (float*)alloc((size_t)gB*gKVH*gNC*64*4);     // -> zprev after scan

  auto cvt = [&](const float* in, unsigned short* o, int n){
    int nb = (n/4 + 255)/256; if (nb > 4096) nb = 4096;
    cvt_kernel<<<dim3(nb), dim3(256), 0, stream>>>(in, o, n);
  };
  cvt(hidden, hbf, gBS*gHID);
  cvt(Wq, wqb, gHID*gHID);
  cvt(Wk, wkvb, 512*gHID);
  cvt(Wv, wkvb + (size_t)512*gHID, 512*gHID);
  cvt(Wo, wob, gHID*gHID);

  gemm_bt<1><<<dim3(64*16), dim3(256), 0, stream>>>(hbf, wqb,  (void*)qproj,  8192, 2048, 2048);
  gemm_bt<1><<<dim3(64*8),  dim3(256), 0, stream>>>(hbf, wkvb, (void*)kvproj, 8192, 1024, 2048);

  rope_kernel<<<dim3((gB*gS*gH*4)/256),   dim3(256), 0, stream>>>(qproj,  cosb, sinb, q_r, gH,   2048);
  rope_kernel<<<dim3((gB*gS*gKVH*4)/256), dim3(256), 0, stream>>>(kvproj, cosb, sinb, k_r, gKVH, 1024);

  transpose64<<<dim3(gB*gKVH*64), dim3(256), 0, stream>>>(k_r,    ktr, 64,   0);
  transpose64<<<dim3(gB*gKVH*64), dim3(256), 0, stream>>>(kvproj, vt,  1024, 1);

  local_attn<<<dim3(gB*gH*64), dim3(256), 0, stream>>>(q_r, k_r, vt, olocal);
  lin_pass1<<<dim3(gB*gKVH*gNC), dim3(256), 0, stream>>>(ktr, vt, kvbuf, ksbuf);
  lin_pass2<<<dim3((gB*gKVH*(4096+64) + 255)/256), dim3(256), 0, stream>>>(kvbuf, kvT, ksbuf);
  lin_pass3<<<dim3(gB*gH*gNC), dim3(256), 0, stream>>>(q_r, k_r, vt, kvT, ksbuf, olin);

  combine_kernel<<<dim3(gBS*gHID/8/256), dim3(256), 0, stream>>>(olocal, olin, hbf, gBS*gHID/8);
  gemm_bt<0><<<dim3(64*16), dim3(256), 0, stream>>>(hbf, wob, (void*)out, 8192, 2048, 2048);
}

// Round 3
// 432.057 us; speedup vs baseline: 1.2304x; 1.1159x over previous
//
#include <hip/hip_runtime.h>

// ---------------- problem constants ----------------
#define gB 2
#define gS 4096
#define gH 32
#define gKVH 8
#define gHID 2048
#define gNC 32            // S / CHK
#define gBS (gB*gS)       // 8192
// D = 64, WIN = 256, CHK = 128, NREP = 4 are hard-coded below.

using bf16x8 = __attribute__((ext_vector_type(8))) short;
using f32x4  = __attribute__((ext_vector_type(4))) float;

__device__ __forceinline__ float bf2f(unsigned short u){
  return __uint_as_float(((unsigned)u) << 16);
}
__device__ __forceinline__ unsigned short f2bf(float f){
  unsigned u = __float_as_uint(f);
  u = (u + 0x7fffu + ((u >> 16) & 1u)) >> 16;   // RNE
  return (unsigned short)u;
}
__device__ __forceinline__ float phi_f(float x){ return x > 0.f ? x + 1.f : __expf(x); } // elu(x)+1

__device__ __forceinline__ void unpack8(uint4 v, unsigned short* o){
  o[0]=(unsigned short)(v.x&0xffffu); o[1]=(unsigned short)(v.x>>16);
  o[2]=(unsigned short)(v.y&0xffffu); o[3]=(unsigned short)(v.y>>16);
  o[4]=(unsigned short)(v.z&0xffffu); o[5]=(unsigned short)(v.z>>16);
  o[6]=(unsigned short)(v.w&0xffffu); o[7]=(unsigned short)(v.w>>16);
}
__device__ __forceinline__ uint4 pack8(const unsigned short* s){
  uint4 v;
  v.x = (unsigned)s[0] | ((unsigned)s[1]<<16);
  v.y = (unsigned)s[2] | ((unsigned)s[3]<<16);
  v.z = (unsigned)s[4] | ((unsigned)s[5]<<16);
  v.w = (unsigned)s[6] | ((unsigned)s[7]<<16);
  return v;
}

// async global->LDS, 16B per lane; LDS dest = wave-uniform base + lane*16
typedef const __attribute__((address_space(1))) void* gas_ptr;
typedef __attribute__((address_space(3))) void* las_ptr;
__device__ __forceinline__ void gload16(const void* g, void* l){
  __builtin_amdgcn_global_load_lds((gas_ptr)g, (las_ptr)l, 16, 0, 0);
}

// ---------------- f32 -> bf16 convert ----------------
__global__ void cvt_kernel(const float* __restrict__ in, unsigned short* __restrict__ out, int n){
  int stride = gridDim.x * blockDim.x;
  for (int i = blockIdx.x*blockDim.x + threadIdx.x; i*4 < n; i += stride){
    float4 v = *(const float4*)(in + (size_t)i*4);
    ushort4 o;
    o.x = f2bf(v.x); o.y = f2bf(v.y); o.z = f2bf(v.z); o.w = f2bf(v.w);
    *(ushort4*)(out + (size_t)i*4) = o;
  }
}

// ---------------- combine two bf16 buffers (a+b) -> bf16 ----------------
__global__ void combine_kernel(const unsigned short* __restrict__ a,
                               const unsigned short* __restrict__ b,
                               unsigned short* __restrict__ o, int n8){
  int i = blockIdx.x*256 + threadIdx.x;
  if (i >= n8) return;
  uint4 va = ((const uint4*)a)[i], vb = ((const uint4*)b)[i];
  unsigned short ta[8], tb[8], to[8];
  unpack8(va, ta); unpack8(vb, tb);
  #pragma unroll
  for (int u = 0; u < 8; ++u) to[u] = f2bf(bf2f(ta[u]) + bf2f(tb[u]));
  ((uint4*)o)[i] = pack8(to);
}

// ---------------- GEMM 256x256 deep pipeline: C[M,N] = A[M,K] * B[N,K]^T ----------------
// 8 waves (2M x 4N), per-wave 128x64 output (8x4 frags of 16x16x32 bf16).
// BK=32, 3 LDS buffers (96 KiB), counted vmcnt(4), raw barriers, setprio MFMA,
// XOR-swizzled LDS (2-way banks) via pre-swizzled global source + swizzled ds_read.
// Stage ledger: tile t+2 staged during tile t into buf (t+2)%3 = (t-1)%3 (free).
// At tile-t boundary vmcnt(4) retires all but t+1's 4 loads -> tile t landed.
template<int OUT_BF16>
__global__ __launch_bounds__(512, 2) void gemm256(const unsigned short* __restrict__ A,
                                                  const unsigned short* __restrict__ Bm,
                                                  void* __restrict__ Cout,
                                                  int Mdim, int Ndim, int Kdim)
{
  __shared__ unsigned short Sh[3*16384];   // buf s: A at s*16384 (256x32), B at +8192
  int tid = threadIdx.x, lane = tid & 63, w = tid >> 6, lr = lane & 15, lg = lane >> 4;
  int wm = w >> 2, wn = w & 3;
  int ntn = Ndim >> 8;
  int nwg = gridDim.x;
  int bid = (int)blockIdx.x;
  int swz = (bid & 7) * (nwg >> 3) + (bid >> 3);   // XCD-chunked (nwg % 8 == 0)
  long m0 = (long)(swz / ntn) * 256;
  long n0 = (long)(swz % ntn) * 256;
  int NT = Kdim >> 5;

  f32x4 acc[8][4] = {};

  auto stage = [&](const unsigned short* G, long r0, int k0, int sbase){
    #pragma unroll
    for (int i = 0; i < 2; ++i){
      int c = w*64 + lane + i*512;            // 16B chunk 0..1023
      int row = c >> 2;                        // 0..255
      int colb = ((c & 3) << 4) ^ (((row >> 1) & 3) << 4);  // pre-swizzled source
      const char* src = (const char*)G + ((r0 + row) * (long)Kdim + k0) * 2 + colb;
      gload16(src, (void*)&Sh[sbase + (w*64 + i*512)*8]);   // linear LDS dest
    }
  };

  // prologue: tiles 0 and 1 (8 loads/thread outstanding)
  stage(A, m0, 0, 0);       stage(Bm, n0, 0, 8192);
  stage(A, m0, 32, 16384);  stage(Bm, n0, 32, 16384 + 8192);

  for (int t = 0; t < NT; ++t){
    int s  = t % 3;
    int sb = s * 16384;
    int sb2 = ((t + 2) % 3) * 16384;
    asm volatile("s_waitcnt vmcnt(4)" ::: "memory");
    __builtin_amdgcn_s_barrier();

    bf16x8 bfr[4];
    #pragma unroll
    for (int n = 0; n < 4; ++n){
      int row = wn*64 + n*16 + lr;
      bfr[n] = *(const bf16x8*)&Sh[sb + 8192 + row*32 + ((lg ^ ((row >> 1) & 3)) << 3)];
    }
    #pragma unroll
    for (int mh = 0; mh < 2; ++mh){
      bf16x8 af[4];
      #pragma unroll
      for (int m = 0; m < 4; ++m){
        int row = wm*128 + mh*64 + m*16 + lr;
        af[m] = *(const bf16x8*)&Sh[sb + row*32 + ((lg ^ ((row >> 1) & 3)) << 3)];
      }
      if (t + 2 < NT){
        if (mh == 0) stage(A,  m0, (t+2)*32, sb2);
        else         stage(Bm, n0, (t+2)*32, sb2 + 8192);
      }
      __builtin_amdgcn_s_barrier();
      __builtin_amdgcn_s_setprio(1);
      #pragma unroll
      for (int m = 0; m < 4; ++m)
        #pragma unroll
        for (int n = 0; n < 4; ++n)
          acc[mh*4+m][n] = __builtin_amdgcn_mfma_f32_16x16x32_bf16(af[m], bfr[n], acc[mh*4+m][n], 0, 0, 0);
      __builtin_amdgcn_s_setprio(0);
      __builtin_amdgcn_s_barrier();
    }
  }
  // epilogue: C/D layout col = lane&15, row = 4*(lane>>4) + reg
  #pragma unroll
  for (int mg = 0; mg < 8; ++mg)
    #pragma unroll
    for (int n = 0; n < 4; ++n)
      #pragma unroll
      for (int r = 0; r < 4; ++r){
        long row = m0 + wm*128 + mg*16 + 4*lg + r;
        long col = n0 + wn*64 + n*16 + lr;
        float v = acc[mg][n][r];
        if (OUT_BF16) ((unsigned short*)Cout)[row*Ndim + col] = f2bf(v);
        else          ((float*)Cout)[row*Ndim + col] = v;
      }
}

// ---------------- RoPE + transpose -> (B,Hx,S,64), bf16 ----------------
__global__ void rope_kernel(const unsigned short* __restrict__ in, const float* __restrict__ cosb,
                            const float* __restrict__ sinb, unsigned short* __restrict__ out,
                            int Hx, int tokstride)
{
  int idx = blockIdx.x*256 + threadIdx.x;
  int total = gB*gS*Hx*4;
  if (idx >= total) return;
  int dq = idx & 3; int h = (idx >> 2) % Hx; int rem = idx / (4*Hx);
  int s = rem % gS; int b = rem / gS;
  int dp = dq*8;
  const unsigned short* ip = in + (size_t)(b*gS+s)*tokstride + h*64;
  unsigned short xlo[8], xhi[8], olo[8], ohi[8];
  unpack8(*(const uint4*)(ip + dp), xlo);
  unpack8(*(const uint4*)(ip + dp + 32), xhi);
  const float* cp = cosb + (size_t)(b*gS+s)*64;
  const float* sp = sinb + (size_t)(b*gS+s)*64;
  #pragma unroll
  for (int u = 0; u < 8; ++u){
    float x1 = bf2f(xlo[u]), x2 = bf2f(xhi[u]);
    float c1 = cp[dp+u], s1 = sp[dp+u], c2 = cp[dp+32+u], s2 = sp[dp+32+u];
    olo[u] = f2bf(x1*c1 - x2*s1);
    ohi[u] = f2bf(x2*c2 + x1*s2);
  }
  unsigned short* op = out + ((size_t)(b*Hx+h)*gS + s)*64;
  *(uint4*)(op + dp)      = pack8(olo);
  *(uint4*)(op + dp + 32) = pack8(ohi);
}

// ---------------- 64x64 tile transpose -> d-major (B,KVH,64,S) ----------------
// mode 0: in = (B,KVH,S,64) rows (k_r).  mode 1: in = fused proj (B,S,tokStride), slice at +voff.
__global__ __launch_bounds__(256) void transpose64(const unsigned short* __restrict__ in,
                                                   unsigned short* __restrict__ out,
                                                   int tokStride, int voff, int mode)
{
  __shared__ unsigned short T[64*72];
  int bid = blockIdx.x;
  int st = bid & 63; int kvh = (bid >> 6) & 7; int b = bid >> 9;
  int s0 = st*64;
  int tid = threadIdx.x;
  const unsigned short* ip;
  size_t tokstr;
  if (mode == 0){ ip = in + ((size_t)(b*gKVH+kvh)*gS + s0)*64;                  tokstr = 64; }
  else          { ip = in + (size_t)(b*gS+s0)*tokStride + voff + kvh*64;        tokstr = tokStride; }
  #pragma unroll
  for (int i = 0; i < 2; ++i){
    int cc = tid + 256*i; int sl = cc >> 3, ch = cc & 7;
    *(uint4*)&T[sl*72 + ch*8] = *(const uint4*)&ip[(size_t)sl*tokstr + ch*8];
  }
  __syncthreads();
  unsigned short* op = out + ((size_t)(b*gKVH+kvh)*64)*gS;
  #pragma unroll
  for (int i = 0; i < 2; ++i){
    int cc = tid + 256*i; int d = cc >> 3, ch = cc & 7;
    unsigned short t[8];
    #pragma unroll
    for (int u = 0; u < 8; ++u) t[u] = T[(ch*8+u)*72 + d];
    *(uint4*)&op[(size_t)d*gS + s0 + ch*8] = pack8(t);
  }
}

// ---------------- local sliding-window attention ----------------
__global__ __launch_bounds__(256) void local_attn(const unsigned short* __restrict__ q_r,
                                                  const unsigned short* __restrict__ k_r,
                                                  const unsigned short* __restrict__ vt,
                                                  unsigned short* __restrict__ olocal)
{
  __shared__ unsigned short Qs[64*72];
  __shared__ unsigned short Ks[64*72];
  __shared__ unsigned short VTs[64*72];
  __shared__ unsigned short Ps[4*16*72];
  int bid = blockIdx.x;
  int qt = bid & 63; int h = (bid >> 6) & 31; int b = bid >> 11;
  int kvh = h >> 2;
  int q0 = qt*64;
  int tid = threadIdx.x, lane = tid & 63, w = tid >> 6, lr = lane & 15, lg = lane >> 4;
  const unsigned short* qp = q_r + ((size_t)(b*gH  +h  )*gS + q0)*64;
  const unsigned short* kp = k_r + ((size_t)(b*gKVH+kvh)*gS)*64;
  const unsigned short* vp = vt  + ((size_t)(b*gKVH+kvh)*64)*gS;   // rows d, stride S

  #pragma unroll
  for (int i = 0; i < 2; ++i){
    int cc = tid + 256*i; int row = cc >> 3, ch = cc & 7;
    *(uint4*)&Qs[row*72 + ch*8] = *(const uint4*)&qp[row*64 + ch*8];
  }
  float mrun[4], lsum[4];
  f32x4 accO[4] = {};
  #pragma unroll
  for (int r = 0; r < 4; ++r){ mrun[r] = -1e30f; lsum[r] = 0.f; }
  int wq = w*16;
  int kt0 = (q0 >= 256) ? 0 : ((256 - q0) >> 6);

  for (int kt = kt0; kt < 5; ++kt){
    int kb = q0 - 256 + kt*64;
    __syncthreads();
    #pragma unroll
    for (int i = 0; i < 2; ++i){
      int cc = tid + 256*i; int row = cc >> 3, ch = cc & 7;
      *(uint4*)&Ks[row*72 + ch*8]  = *(const uint4*)&kp[(size_t)(kb+row)*64 + ch*8];
      *(uint4*)&VTs[row*72 + ch*8] = *(const uint4*)&vp[(size_t)row*gS + kb + ch*8];
    }
    __syncthreads();

    f32x4 sc[4] = {};
    #pragma unroll
    for (int kk = 0; kk < 64; kk += 32){
      bf16x8 aq = *(const bf16x8*)&Qs[(wq+lr)*72 + kk + 8*lg];
      #pragma unroll
      for (int f = 0; f < 4; ++f){
        bf16x8 bk = *(const bf16x8*)&Ks[(f*16+lr)*72 + kk + 8*lg];
        sc[f] = __builtin_amdgcn_mfma_f32_16x16x32_bf16(aq, bk, sc[f], 0, 0, 0);
      }
    }
    float rmax[4]; bool keepM[4][4];
    #pragma unroll
    for (int r = 0; r < 4; ++r) rmax[r] = -1e30f;
    #pragma unroll
    for (int f = 0; f < 4; ++f)
      #pragma unroll
      for (int r = 0; r < 4; ++r){
        int i = wq + 4*lg + r;
        int j = kt*64 + f*16 + lr;
        bool keep = (j > i) && (j <= i + 256);
        keepM[f][r] = keep;
        float s = sc[f][r]*0.125f;
        s = keep ? s : -1e30f;
        sc[f][r] = s;
        rmax[r] = fmaxf(rmax[r], s);
      }
    #pragma unroll
    for (int off = 1; off < 16; off <<= 1)
      #pragma unroll
      for (int r = 0; r < 4; ++r) rmax[r] = fmaxf(rmax[r], __shfl_xor(rmax[r], off));
    float psum[4];
    #pragma unroll
    for (int r = 0; r < 4; ++r){
      float mn = fmaxf(mrun[r], rmax[r]);
      float al = __expf(mrun[r] - mn);
      mrun[r] = mn;
      lsum[r] *= al;
      #pragma unroll
      for (int dt = 0; dt < 4; ++dt) accO[dt][r] *= al;
      psum[r] = 0.f;
    }
    #pragma unroll
    for (int f = 0; f < 4; ++f)
      #pragma unroll
      for (int r = 0; r < 4; ++r){
        float p = keepM[f][r] ? __expf(sc[f][r] - mrun[r]) : 0.f;
        psum[r] += p;
        Ps[w*1152 + (4*lg + r)*72 + f*16 + lr] = f2bf(p);
      }
    #pragma unroll
    for (int off = 1; off < 16; off <<= 1)
      #pragma unroll
      for (int r = 0; r < 4; ++r) psum[r] += __shfl_xor(psum[r], off);
    #pragma unroll
    for (int r = 0; r < 4; ++r) lsum[r] += psum[r];
    // Ps write->read is same-wave LDS (in-order DS pipe) — no barrier needed.
    #pragma unroll
    for (int kk = 0; kk < 64; kk += 32){
      bf16x8 ap = *(const bf16x8*)&Ps[w*1152 + lr*72 + kk + 8*lg];
      #pragma unroll
      for (int dt = 0; dt < 4; ++dt){
        bf16x8 bv = *(const bf16x8*)&VTs[(dt*16+lr)*72 + kk + 8*lg];
        accO[dt] = __builtin_amdgcn_mfma_f32_16x16x32_bf16(ap, bv, accO[dt], 0, 0, 0);
      }
    }
  }
  #pragma unroll
  for (int dt = 0; dt < 4; ++dt)
    #pragma unroll
    for (int r = 0; r < 4; ++r){
      int s = q0 + wq + 4*lg + r;
      int d = dt*16 + lr;
      float o = accO[dt][r] / lsum[r];
      olocal[((size_t)(b*gS+s)*gH + h)*64 + d] = f2bf(0.5f * o);
    }
}

// ---------------- linear attention pass 1 ----------------
__global__ __launch_bounds__(256) void lin_pass1(const unsigned short* __restrict__ ktr,
                                                 const unsigned short* __restrict__ vt,
                                                 float* __restrict__ kvbuf, float* __restrict__ ksbuf)
{
  __shared__ unsigned short pkT[64*136];
  __shared__ unsigned short vT[64*136];
  int bid = blockIdx.x;
  int c = bid & 31; int kvh = (bid >> 5) & 7; int b = bid >> 8;
  int tid = threadIdx.x, lane = tid & 63, w = tid >> 6, lr = lane & 15, lg = lane >> 4;
  int s0 = c*128;
  const unsigned short* kp = ktr + ((size_t)(b*gKVH+kvh)*64)*gS;
  const unsigned short* vp = vt  + ((size_t)(b*gKVH+kvh)*64)*gS;
  #pragma unroll
  for (int i = 0; i < 4; ++i){
    int cc = tid + 256*i; int d = cc >> 4, ch = cc & 15;
    unsigned short t[8]; unpack8(*(const uint4*)&kp[(size_t)d*gS + s0 + ch*8], t);
    #pragma unroll
    for (int u = 0; u < 8; ++u) t[u] = f2bf(phi_f(bf2f(t[u])));
    *(uint4*)&pkT[d*136 + ch*8] = pack8(t);
    *(uint4*)&vT[d*136 + ch*8]  = *(const uint4*)&vp[(size_t)d*gS + s0 + ch*8];
  }
  __syncthreads();
  f32x4 acc[4] = {};
  #pragma unroll
  for (int kk = 0; kk < 128; kk += 32){
    bf16x8 a = *(const bf16x8*)&pkT[(16*w+lr)*136 + kk + 8*lg];
    #pragma unroll
    for (int et = 0; et < 4; ++et){
      bf16x8 bv = *(const bf16x8*)&vT[(16*et+lr)*136 + kk + 8*lg];
      acc[et] = __builtin_amdgcn_mfma_f32_16x16x32_bf16(a, bv, acc[et], 0, 0, 0);
    }
  }
  size_t base = (size_t)((b*gKVH+kvh)*gNC + c);
  float* kvp = kvbuf + base*4096;
  #pragma unroll
  for (int et = 0; et < 4; ++et)
    #pragma unroll
    for (int r = 0; r < 4; ++r)
      kvp[(16*w + 4*lg + r)*64 + 16*et + lr] = acc[et][r];   // d-major [d][e]
  if (tid < 64){
    float sum = 0.f;
    for (int k = 0; k < 128; ++k) sum += bf2f(pkT[tid*136 + k]);
    ksbuf[base*64 + tid] = sum;
  }
}

// ---------------- linear attention pass 2: exclusive scan; kv transposed to e-major ----------------
__global__ void lin_pass2(const float* __restrict__ kvin, float* __restrict__ kvout,
                          float* __restrict__ ksbuf){
  int t = blockIdx.x*256 + threadIdx.x;
  const int per = 4096 + 64;
  if (t >= gB*gKVH*per) return;
  int bh = t / per; int e = t % per;
  if (e < 4096){
    int d = e >> 6, ecol = e & 63;
    const float* p = kvin  + (size_t)bh*gNC*4096 + e;
    float* q       = kvout + (size_t)bh*gNC*4096 + ecol*64 + d;
    float acc = 0.f;
    for (int cix = 0; cix < gNC; ++cix){ float v = p[(size_t)cix*4096]; q[(size_t)cix*4096] = acc; acc += v; }
  } else {
    float* p = ksbuf + (size_t)bh*gNC*64 + (e - 4096);
    float acc = 0.f;
    for (int cix = 0; cix < gNC; ++cix){ float v = p[cix*64]; p[cix*64] = acc; acc += v; }
  }
}

// ---------------- linear attention pass 3 ----------------
__global__ __launch_bounds__(256) void lin_pass3(const unsigned short* __restrict__ q_r,
                                                 const unsigned short* __restrict__ k_r,
                                                 const unsigned short* __restrict__ vt,
                                                 const float* __restrict__ SprevT,
                                                 const float* __restrict__ zprev,
                                                 unsigned short* __restrict__ olin)
{
  __shared__ unsigned short pq[128*72];
  __shared__ unsigned short pk[64*72];
  __shared__ unsigned short Ph[128*72];
  __shared__ unsigned short vT[64*72];
  __shared__ unsigned short SpT[64*72];
  __shared__ float zp[64];

  int bid = blockIdx.x;
  int c = bid & 31; int h = (bid >> 5) & 31; int b = bid >> 10;
  int kvh = h >> 2;
  int tid = threadIdx.x, lane = tid & 63, w = tid >> 6, lr = lane & 15, lg = lane >> 4;
  int s0 = c*128;
  const unsigned short* qp = q_r + ((size_t)(b*gH  +h  )*gS + s0)*64;
  const unsigned short* kp = k_r + ((size_t)(b*gKVH+kvh)*gS + s0)*64;
  const unsigned short* vp = vt  + ((size_t)(b*gKVH+kvh)*64)*gS;
  const float* Sp  = SprevT + ((size_t)((b*gKVH+kvh)*gNC + c))*4096;
  const float* zpg = zprev  + ((size_t)((b*gKVH+kvh)*gNC + c))*64;

  #pragma unroll
  for (int i = 0; i < 4; ++i){
    int cc = tid + 256*i; int row = cc >> 3, d0 = (cc & 7)*8;
    unsigned short t[8]; unpack8(*(const uint4*)(qp + row*64 + d0), t);
    #pragma unroll
    for (int u = 0; u < 8; ++u) pq[row*72 + d0 + u] = f2bf(phi_f(bf2f(t[u])));
  }
  #pragma unroll
  for (int i = 0; i < 16; ++i){
    int f = tid + 256*i; int e = f >> 6, d = f & 63;
    SpT[e*72 + d] = f2bf(Sp[f]);
  }
  if (tid < 64) zp[tid] = zpg[tid];

  float den[2][4] = {};
  f32x4 accO[2][4] = {};

  for (int kh = 0; kh < 2; ++kh){
    __syncthreads();
    #pragma unroll
    for (int i = 0; i < 2; ++i){
      int cc = tid + 256*i; int kr = cc >> 3, d0 = (cc & 7)*8;
      unsigned short t[8]; unpack8(*(const uint4*)(kp + (kh*64+kr)*64 + d0), t);
      #pragma unroll
      for (int u = 0; u < 8; ++u) pk[kr*72 + d0 + u] = f2bf(phi_f(bf2f(t[u])));
      *(uint4*)&vT[kr*72 + d0] = *(const uint4*)&vp[(size_t)kr*gS + s0 + kh*64 + d0];
    }
    __syncthreads();

    f32x4 sc[2][4] = {};
    #pragma unroll
    for (int kk = 0; kk < 64; kk += 32){
      bf16x8 a[2];
      #pragma unroll
      for (int rt = 0; rt < 2; ++rt) a[rt] = *(const bf16x8*)&pq[(32*w+16*rt+lr)*72 + kk + 8*lg];
      #pragma unroll
      for (int ct = 0; ct < 4; ++ct){
        bf16x8 bk = *(const bf16x8*)&pk[(16*ct+lr)*72 + kk + 8*lg];
        #pragma unroll
        for (int rt = 0; rt < 2; ++rt)
          sc[rt][ct] = __builtin_amdgcn_mfma_f32_16x16x32_bf16(a[rt], bk, sc[rt][ct], 0, 0, 0);
      }
    }
    #pragma unroll
    for (int rt = 0; rt < 2; ++rt)
      #pragma unroll
      for (int ct = 0; ct < 4; ++ct)
        #pragma unroll
        for (int r = 0; r < 4; ++r){
          int qrow = 32*w + 16*rt + 4*lg + r;
          int krow = kh*64 + 16*ct + lr;
          float sv = (krow <= qrow) ? sc[rt][ct][r] : 0.f;
          den[rt][r] += sv;
          Ph[qrow*72 + 16*ct + lr] = f2bf(sv);
        }
    #pragma unroll
    for (int kk = 0; kk < 64; kk += 32){
      bf16x8 ap[2];
      #pragma unroll
      for (int rt = 0; rt < 2; ++rt) ap[rt] = *(const bf16x8*)&Ph[(32*w+16*rt+lr)*72 + kk + 8*lg];
      #pragma unroll
      for (int et = 0; et < 4; ++et){
        bf16x8 bv = *(const bf16x8*)&vT[(16*et+lr)*72 + kk + 8*lg];
        #pragma unroll
        for (int rt = 0; rt < 2; ++rt)
          accO[rt][et] = __builtin_amdgcn_mfma_f32_16x16x32_bf16(ap[rt], bv, accO[rt][et], 0, 0, 0);
      }
    }
  }
  #pragma unroll
  for (int kk = 0; kk < 64; kk += 32){
    bf16x8 a[2];
    #pragma unroll
    for (int rt = 0; rt < 2; ++rt) a[rt] = *(const bf16x8*)&pq[(32*w+16*rt+lr)*72 + kk + 8*lg];
    #pragma unroll
    for (int et = 0; et < 4; ++et){
      bf16x8 bs = *(const bf16x8*)&SpT[(16*et+lr)*72 + kk + 8*lg];
      #pragma unroll
      for (int rt = 0; rt < 2; ++rt)
        accO[rt][et] = __builtin_amdgcn_mfma_f32_16x16x32_bf16(a[rt], bs, accO[rt][et], 0, 0, 0);
    }
  }
  #pragma unroll
  for (int rt = 0; rt < 2; ++rt)
    #pragma unroll
    for (int r = 0; r < 4; ++r){
      int qrow = 32*w + 16*rt + 4*lg + r;
      float part = 0.f;
      #pragma unroll
      for (int u = 0; u < 4; ++u){
        int d = 4*lr + u;
        part += bf2f(pq[qrow*72 + d]) * zp[d];
      }
      den[rt][r] += part;
      #pragma unroll
      for (int off = 1; off < 16; off <<= 1)
        den[rt][r] += __shfl_xor(den[rt][r], off);
    }
  #pragma unroll
  for (int rt = 0; rt < 2; ++rt)
    #pragma unroll
    for (int et = 0; et < 4; ++et)
      #pragma unroll
      for (int r = 0; r < 4; ++r){
        int qrow = 32*w + 16*rt + 4*lg + r;
        int e = 16*et + lr;
        float o = accO[rt][et][r] / (den[rt][r] + 1e-6f);
        int s = s0 + qrow;
        olin[((size_t)(b*gS+s)*gH + h)*64 + e] = f2bf(0.5f * o);
      }
}

// ---------------- host launch ----------------
extern "C" void kernel_launch(void* const* d_in, const int* in_sizes, int n_in,
                              void* d_out, int out_size, void* d_ws, size_t ws_size,
                              hipStream_t stream)
{
  const float* hidden = (const float*)d_in[0];
  const float* cosb   = (const float*)d_in[1];
  const float* sinb   = (const float*)d_in[2];
  const float* Wq     = (const float*)d_in[3];
  const float* Wk     = (const float*)d_in[4];
  const float* Wv     = (const float*)d_in[5];
  const float* Wo     = (const float*)d_in[6];
  float* out = (float*)d_out;

  char* ws = (char*)d_ws;
  size_t off = 0;
  auto alloc = [&](size_t bytes)->void*{
    void* p = ws + off; off += (bytes + 255) & ~(size_t)255; return p;
  };
  unsigned short* hbf    = (unsigned short*)alloc((size_t)gBS*gHID*2);   // hidden bf16; reused as hybrid bf16
  unsigned short* wqkv   = (unsigned short*)alloc((size_t)3072*gHID*2);  // [Wq;Wk;Wv]
  unsigned short* wob    = (unsigned short*)alloc((size_t)gHID*gHID*2);
  unsigned short* qkv    = (unsigned short*)alloc((size_t)gBS*3072*2);   // (B,S,[q|k|v])
  unsigned short* q_r    = (unsigned short*)alloc((size_t)gBS*gHID*2);   // (B,H,S,64)
  unsigned short* k_r    = (unsigned short*)alloc((size_t)gBS*512*2);    // (B,KVH,S,64)
  unsigned short* ktr    = (unsigned short*)alloc((size_t)gBS*512*2);    // (B,KVH,64,S)
  unsigned short* vt     = (unsigned short*)alloc((size_t)gBS*512*2);    // (B,KVH,64,S)
  unsigned short* olocal = (unsigned short*)alloc((size_t)gBS*gHID*2);
  unsigned short* olin   = (unsigned short*)alloc((size_t)gBS*gHID*2);
  float* kvbuf           = (float*)alloc((size_t)gB*gKVH*gNC*4096*4);
  float* kvT             = (float*)alloc((size_t)gB*gKVH*gNC*4096*4);
  float* ksbuf           = (float*)alloc((size_t)gB*gKVH*gNC*64*4);

  auto cvt = [&](const float* in, unsigned short* o, int n){
    int nb = (n/4 + 255)/256; if (nb > 4096) nb = 4096;
    cvt_kernel<<<dim3(nb), dim3(256), 0, stream>>>(in, o, n);
  };
  cvt(hidden, hbf, gBS*gHID);
  cvt(Wq, wqkv, gHID*gHID);
  cvt(Wk, wqkv + (size_t)2048*gHID, 512*gHID);
  cvt(Wv, wqkv + (size_t)2560*gHID, 512*gHID);
  cvt(Wo, wob, gHID*gHID);

  gemm256<1><<<dim3(32*12), dim3(512), 0, stream>>>(hbf, wqkv, (void*)qkv, 8192, 3072, 2048);

  rope_kernel<<<dim3((gB*gS*gH*4)/256),   dim3(256), 0, stream>>>(qkv,        cosb, sinb, q_r, gH,   3072);
  rope_kernel<<<dim3((gB*gS*gKVH*4)/256), dim3(256), 0, stream>>>(qkv + 2048, cosb, sinb, k_r, gKVH, 3072);

  transpose64<<<dim3(gB*gKVH*64), dim3(256), 0, stream>>>(k_r, ktr, 64,   0,    0);
  transpose64<<<dim3(gB*gKVH*64), dim3(256), 0, stream>>>(qkv, vt,  3072, 2560, 1);

  local_attn<<<dim3(gB*gH*64), dim3(256), 0, stream>>>(q_r, k_r, vt, olocal);
  lin_pass1<<<dim3(gB*gKVH*gNC), dim3(256), 0, stream>>>(ktr, vt, kvbuf, ksbuf);
  lin_pass2<<<dim3((gB*gKVH*(4096+64) + 255)/256), dim3(256), 0, stream>>>(kvbuf, kvT, ksbuf);
  lin_pass3<<<dim3(gB*gH*gNC), dim3(256), 0, stream>>>(q_r, k_r, vt, kvT, ksbuf, olin);

  combine_kernel<<<dim3(gBS*gHID/8/256), dim3(256), 0, stream>>>(olocal, olin, hbf, gBS*gHID/8);
  gemm256<0><<<dim3(32*8), dim3(512), 0, stream>>>(hbf, wob, (void*)out, 8192, 2048, 2048);
}

// Round 4
// 421.855 us; speedup vs baseline: 1.2602x; 1.0242x over previous
//
#include <hip/hip_runtime.h>

// ---------------- problem constants ----------------
#define gB 2
#define gS 4096
#define gH 32
#define gKVH 8
#define gHID 2048
#define gNC 32            // S / CHK
#define gBS (gB*gS)       // 8192
// D = 64, WIN = 256, CHK = 128, NREP = 4 are hard-coded below.

using bf16x8 = __attribute__((ext_vector_type(8))) short;
using f32x4  = __attribute__((ext_vector_type(4))) float;

__device__ __forceinline__ float bf2f(unsigned short u){
  return __uint_as_float(((unsigned)u) << 16);
}
__device__ __forceinline__ unsigned short f2bf(float f){
  unsigned u = __float_as_uint(f);
  u = (u + 0x7fffu + ((u >> 16) & 1u)) >> 16;   // RNE
  return (unsigned short)u;
}
__device__ __forceinline__ float phi_f(float x){ return x > 0.f ? x + 1.f : __expf(x); } // elu(x)+1

__device__ __forceinline__ void unpack8(uint4 v, unsigned short* o){
  o[0]=(unsigned short)(v.x&0xffffu); o[1]=(unsigned short)(v.x>>16);
  o[2]=(unsigned short)(v.y&0xffffu); o[3]=(unsigned short)(v.y>>16);
  o[4]=(unsigned short)(v.z&0xffffu); o[5]=(unsigned short)(v.z>>16);
  o[6]=(unsigned short)(v.w&0xffffu); o[7]=(unsigned short)(v.w>>16);
}
__device__ __forceinline__ uint4 pack8(const unsigned short* s){
  uint4 v;
  v.x = (unsigned)s[0] | ((unsigned)s[1]<<16);
  v.y = (unsigned)s[2] | ((unsigned)s[3]<<16);
  v.z = (unsigned)s[4] | ((unsigned)s[5]<<16);
  v.w = (unsigned)s[6] | ((unsigned)s[7]<<16);
  return v;
}

// async global->LDS, 16B per lane; LDS dest = wave-uniform base + lane*16
typedef const __attribute__((address_space(1))) void* gas_ptr;
typedef __attribute__((address_space(3))) void* las_ptr;
__device__ __forceinline__ void gload16(const void* g, void* l){
  __builtin_amdgcn_global_load_lds((gas_ptr)g, (las_ptr)l, 16, 0, 0);
}

// ---------------- f32 -> bf16 convert ----------------
__global__ void cvt_kernel(const float* __restrict__ in, unsigned short* __restrict__ out, int n){
  int stride = gridDim.x * blockDim.x;
  for (int i = blockIdx.x*blockDim.x + threadIdx.x; i*4 < n; i += stride){
    float4 v = *(const float4*)(in + (size_t)i*4);
    ushort4 o;
    o.x = f2bf(v.x); o.y = f2bf(v.y); o.z = f2bf(v.z); o.w = f2bf(v.w);
    *(ushort4*)(out + (size_t)i*4) = o;
  }
}

// ---------------- combine two bf16 buffers (a+b) -> bf16 ----------------
__global__ void combine_kernel(const unsigned short* __restrict__ a,
                               const unsigned short* __restrict__ b,
                               unsigned short* __restrict__ o, int n8){
  int i = blockIdx.x*256 + threadIdx.x;
  if (i >= n8) return;
  uint4 va = ((const uint4*)a)[i], vb = ((const uint4*)b)[i];
  unsigned short ta[8], tb[8], to[8];
  unpack8(va, ta); unpack8(vb, tb);
  #pragma unroll
  for (int u = 0; u < 8; ++u) to[u] = f2bf(bf2f(ta[u]) + bf2f(tb[u]));
  ((uint4*)o)[i] = pack8(to);
}

// ---------------- GEMM 128x256 deep pipeline: C[M,N] = A[M,K] * B[N,K]^T ----------------
// 8 waves (2M x 4N), per-wave 64x64 output (4x4 frags of 16x16x32 bf16).
// BK=32, 4 LDS buffers of 24KB (A 128x32 + B 256x32) = 96 KiB, prefetch depth 3.
// One barrier per K-tile; counted vmcnt (3 loads/thread/tile, steady wait = 6);
// tail iterations use vmcnt(3)/vmcnt(0). setprio around the MFMA cluster.
// Both-sides XOR swizzle (chunk ^= (row>>1)&3) -> bank-conflict-free ds_read_b128.
// Ledger: stage(t+3) issued AFTER barrier of tile t, into buf (t+3)%4 = (t-1)%4,
// whose readers all passed that barrier. vmcnt(6)+barrier => tile t fully landed.
template<int OUT_BF16>
__global__ __launch_bounds__(512, 1) void gemm128(const unsigned short* __restrict__ A,
                                                  const unsigned short* __restrict__ Bm,
                                                  void* __restrict__ Cout,
                                                  int Mdim, int Ndim, int Kdim)
{
  __shared__ unsigned short Sh[4*12288];   // buf s: A at s*12288 (128x32), B at +4096 (256x32)
  int tid = threadIdx.x, lane = tid & 63, w = tid >> 6, lr = lane & 15, lg = lane >> 4;
  int wm = w >> 2, wn = w & 3;
  int ntn = Ndim >> 8;
  int nwg = gridDim.x;
  int bid = (int)blockIdx.x;
  int swz = (bid & 7) * (nwg >> 3) + (bid >> 3);   // XCD-chunked (nwg % 8 == 0)
  long m0 = (long)(swz / ntn) * 128;
  long n0 = (long)(swz % ntn) * 256;
  int NT = Kdim >> 5;

  f32x4 acc[4][4] = {};

  auto stage = [&](int t){
    int sbase = (t & 3) * 12288;
    int k0 = t << 5;
    {
      int c = w*64 + lane;                     // chunk 0..511 (A: 128 rows x 4)
      int row = c >> 2;
      int colb = ((c & 3) << 4) ^ (((row >> 1) & 3) << 4);
      gload16((const char*)A + ((m0 + row) * (long)Kdim + k0) * 2 + colb,
              (void*)&Sh[sbase + w*512]);
    }
    #pragma unroll
    for (int i = 0; i < 2; ++i){
      int c = w*64 + lane + i*512;             // chunk 0..1023 (B: 256 rows x 4)
      int row = c >> 2;
      int colb = ((c & 3) << 4) ^ (((row >> 1) & 3) << 4);
      gload16((const char*)Bm + ((n0 + row) * (long)Kdim + k0) * 2 + colb,
              (void*)&Sh[sbase + 4096 + w*512 + i*4096]);
    }
  };

  auto body = [&](int t){
    int sb = (t & 3) * 12288;
    __builtin_amdgcn_s_barrier();
    if (t + 3 < NT) stage(t + 3);
    bf16x8 af[4], bfr[4];
    #pragma unroll
    for (int m = 0; m < 4; ++m){
      int row = wm*64 + m*16 + lr;
      af[m] = *(const bf16x8*)&Sh[sb + row*32 + ((lg ^ ((row >> 1) & 3)) << 3)];
    }
    #pragma unroll
    for (int n = 0; n < 4; ++n){
      int row = wn*64 + n*16 + lr;
      bfr[n] = *(const bf16x8*)&Sh[sb + 4096 + row*32 + ((lg ^ ((row >> 1) & 3)) << 3)];
    }
    __builtin_amdgcn_s_setprio(1);
    #pragma unroll
    for (int m = 0; m < 4; ++m)
      #pragma unroll
      for (int n = 0; n < 4; ++n)
        acc[m][n] = __builtin_amdgcn_mfma_f32_16x16x32_bf16(af[m], bfr[n], acc[m][n], 0, 0, 0);
    __builtin_amdgcn_s_setprio(0);
  };

  // prologue: tiles 0..2 in flight (9 loads/thread)
  stage(0); stage(1); stage(2);
  for (int t = 0; t < NT - 2; ++t){
    asm volatile("s_waitcnt vmcnt(6)" ::: "memory");
    body(t);
  }
  asm volatile("s_waitcnt vmcnt(3)" ::: "memory");
  body(NT - 2);
  asm volatile("s_waitcnt vmcnt(0)" ::: "memory");
  body(NT - 1);

  // epilogue: C/D layout col = lane&15, row = 4*(lane>>4) + reg
  #pragma unroll
  for (int m = 0; m < 4; ++m)
    #pragma unroll
    for (int n = 0; n < 4; ++n)
      #pragma unroll
      for (int r = 0; r < 4; ++r){
        long row = m0 + wm*64 + m*16 + 4*lg + r;
        long col = n0 + wn*64 + n*16 + lr;
        float v = acc[m][n][r];
        if (OUT_BF16) ((unsigned short*)Cout)[row*Ndim + col] = f2bf(v);
        else          ((float*)Cout)[row*Ndim + col] = v;
      }
}

// ---------------- RoPE + transpose -> (B,Hx,S,64), bf16 ----------------
__global__ void rope_kernel(const unsigned short* __restrict__ in, const float* __restrict__ cosb,
                            const float* __restrict__ sinb, unsigned short* __restrict__ out,
                            int Hx, int tokstride)
{
  int idx = blockIdx.x*256 + threadIdx.x;
  int total = gB*gS*Hx*4;
  if (idx >= total) return;
  int dq = idx & 3; int h = (idx >> 2) % Hx; int rem = idx / (4*Hx);
  int s = rem % gS; int b = rem / gS;
  int dp = dq*8;
  const unsigned short* ip = in + (size_t)(b*gS+s)*tokstride + h*64;
  unsigned short xlo[8], xhi[8], olo[8], ohi[8];
  unpack8(*(const uint4*)(ip + dp), xlo);
  unpack8(*(const uint4*)(ip + dp + 32), xhi);
  const float* cp = cosb + (size_t)(b*gS+s)*64;
  const float* sp = sinb + (size_t)(b*gS+s)*64;
  #pragma unroll
  for (int u = 0; u < 8; ++u){
    float x1 = bf2f(xlo[u]), x2 = bf2f(xhi[u]);
    float c1 = cp[dp+u], s1 = sp[dp+u], c2 = cp[dp+32+u], s2 = sp[dp+32+u];
    olo[u] = f2bf(x1*c1 - x2*s1);
    ohi[u] = f2bf(x2*c2 + x1*s2);
  }
  unsigned short* op = out + ((size_t)(b*Hx+h)*gS + s)*64;
  *(uint4*)(op + dp)      = pack8(olo);
  *(uint4*)(op + dp + 32) = pack8(ohi);
}

// ---------------- 64x64 tile transpose -> d-major (B,KVH,64,S) ----------------
// mode 0: in = (B,KVH,S,64) rows (k_r).  mode 1: in = fused proj (B,S,tokStride), slice at +voff.
__global__ __launch_bounds__(256) void transpose64(const unsigned short* __restrict__ in,
                                                   unsigned short* __restrict__ out,
                                                   int tokStride, int voff, int mode)
{
  __shared__ unsigned short T[64*72];
  int bid = blockIdx.x;
  int st = bid & 63; int kvh = (bid >> 6) & 7; int b = bid >> 9;
  int s0 = st*64;
  int tid = threadIdx.x;
  const unsigned short* ip;
  size_t tokstr;
  if (mode == 0){ ip = in + ((size_t)(b*gKVH+kvh)*gS + s0)*64;                  tokstr = 64; }
  else          { ip = in + (size_t)(b*gS+s0)*tokStride + voff + kvh*64;        tokstr = tokStride; }
  #pragma unroll
  for (int i = 0; i < 2; ++i){
    int cc = tid + 256*i; int sl = cc >> 3, ch = cc & 7;
    *(uint4*)&T[sl*72 + ch*8] = *(const uint4*)&ip[(size_t)sl*tokstr + ch*8];
  }
  __syncthreads();
  unsigned short* op = out + ((size_t)(b*gKVH+kvh)*64)*gS;
  #pragma unroll
  for (int i = 0; i < 2; ++i){
    int cc = tid + 256*i; int d = cc >> 3, ch = cc & 7;
    unsigned short t[8];
    #pragma unroll
    for (int u = 0; u < 8; ++u) t[u] = T[(ch*8+u)*72 + d];
    *(uint4*)&op[(size_t)d*gS + s0 + ch*8] = pack8(t);
  }
}

// ---------------- local sliding-window attention ----------------
__global__ __launch_bounds__(256) void local_attn(const unsigned short* __restrict__ q_r,
                                                  const unsigned short* __restrict__ k_r,
                                                  const unsigned short* __restrict__ vt,
                                                  unsigned short* __restrict__ olocal)
{
  __shared__ unsigned short Qs[64*72];
  __shared__ unsigned short Ks[64*72];
  __shared__ unsigned short VTs[64*72];
  __shared__ unsigned short Ps[4*16*72];
  int bid = blockIdx.x;
  int qt = bid & 63; int h = (bid >> 6) & 31; int b = bid >> 11;
  int kvh = h >> 2;
  int q0 = qt*64;
  int tid = threadIdx.x, lane = tid & 63, w = tid >> 6, lr = lane & 15, lg = lane >> 4;
  const unsigned short* qp = q_r + ((size_t)(b*gH  +h  )*gS + q0)*64;
  const unsigned short* kp = k_r + ((size_t)(b*gKVH+kvh)*gS)*64;
  const unsigned short* vp = vt  + ((size_t)(b*gKVH+kvh)*64)*gS;   // rows d, stride S

  #pragma unroll
  for (int i = 0; i < 2; ++i){
    int cc = tid + 256*i; int row = cc >> 3, ch = cc & 7;
    *(uint4*)&Qs[row*72 + ch*8] = *(const uint4*)&qp[row*64 + ch*8];
  }
  float mrun[4], lsum[4];
  f32x4 accO[4] = {};
  #pragma unroll
  for (int r = 0; r < 4; ++r){ mrun[r] = -1e30f; lsum[r] = 0.f; }
  int wq = w*16;
  int kt0 = (q0 >= 256) ? 0 : ((256 - q0) >> 6);

  for (int kt = kt0; kt < 5; ++kt){
    int kb = q0 - 256 + kt*64;
    __syncthreads();
    #pragma unroll
    for (int i = 0; i < 2; ++i){
      int cc = tid + 256*i; int row = cc >> 3, ch = cc & 7;
      *(uint4*)&Ks[row*72 + ch*8]  = *(const uint4*)&kp[(size_t)(kb+row)*64 + ch*8];
      *(uint4*)&VTs[row*72 + ch*8] = *(const uint4*)&vp[(size_t)row*gS + kb + ch*8];
    }
    __syncthreads();

    f32x4 sc[4] = {};
    #pragma unroll
    for (int kk = 0; kk < 64; kk += 32){
      bf16x8 aq = *(const bf16x8*)&Qs[(wq+lr)*72 + kk + 8*lg];
      #pragma unroll
      for (int f = 0; f < 4; ++f){
        bf16x8 bk = *(const bf16x8*)&Ks[(f*16+lr)*72 + kk + 8*lg];
        sc[f] = __builtin_amdgcn_mfma_f32_16x16x32_bf16(aq, bk, sc[f], 0, 0, 0);
      }
    }
    float rmax[4]; bool keepM[4][4];
    #pragma unroll
    for (int r = 0; r < 4; ++r) rmax[r] = -1e30f;
    #pragma unroll
    for (int f = 0; f < 4; ++f)
      #pragma unroll
      for (int r = 0; r < 4; ++r){
        int i = wq + 4*lg + r;
        int j = kt*64 + f*16 + lr;
        bool keep = (j > i) && (j <= i + 256);
        keepM[f][r] = keep;
        float s = sc[f][r]*0.125f;
        s = keep ? s : -1e30f;
        sc[f][r] = s;
        rmax[r] = fmaxf(rmax[r], s);
      }
    #pragma unroll
    for (int off = 1; off < 16; off <<= 1)
      #pragma unroll
      for (int r = 0; r < 4; ++r) rmax[r] = fmaxf(rmax[r], __shfl_xor(rmax[r], off));
    float psum[4];
    #pragma unroll
    for (int r = 0; r < 4; ++r){
      float mn = fmaxf(mrun[r], rmax[r]);
      float al = __expf(mrun[r] - mn);
      mrun[r] = mn;
      lsum[r] *= al;
      #pragma unroll
      for (int dt = 0; dt < 4; ++dt) accO[dt][r] *= al;
      psum[r] = 0.f;
    }
    #pragma unroll
    for (int f = 0; f < 4; ++f)
      #pragma unroll
      for (int r = 0; r < 4; ++r){
        float p = keepM[f][r] ? __expf(sc[f][r] - mrun[r]) : 0.f;
        psum[r] += p;
        Ps[w*1152 + (4*lg + r)*72 + f*16 + lr] = f2bf(p);
      }
    #pragma unroll
    for (int off = 1; off < 16; off <<= 1)
      #pragma unroll
      for (int r = 0; r < 4; ++r) psum[r] += __shfl_xor(psum[r], off);
    #pragma unroll
    for (int r = 0; r < 4; ++r) lsum[r] += psum[r];
    // Ps write->read is same-wave LDS (in-order DS pipe) — no barrier needed.
    #pragma unroll
    for (int kk = 0; kk < 64; kk += 32){
      bf16x8 ap = *(const bf16x8*)&Ps[w*1152 + lr*72 + kk + 8*lg];
      #pragma unroll
      for (int dt = 0; dt < 4; ++dt){
        bf16x8 bv = *(const bf16x8*)&VTs[(dt*16+lr)*72 + kk + 8*lg];
        accO[dt] = __builtin_amdgcn_mfma_f32_16x16x32_bf16(ap, bv, accO[dt], 0, 0, 0);
      }
    }
  }
  #pragma unroll
  for (int dt = 0; dt < 4; ++dt)
    #pragma unroll
    for (int r = 0; r < 4; ++r){
      int s = q0 + wq + 4*lg + r;
      int d = dt*16 + lr;
      float o = accO[dt][r] / lsum[r];
      olocal[((size_t)(b*gS+s)*gH + h)*64 + d] = f2bf(0.5f * o);
    }
}

// ---------------- linear attention pass 1 ----------------
__global__ __launch_bounds__(256) void lin_pass1(const unsigned short* __restrict__ ktr,
                                                 const unsigned short* __restrict__ vt,
                                                 float* __restrict__ kvbuf, float* __restrict__ ksbuf)
{
  __shared__ unsigned short pkT[64*136];
  __shared__ unsigned short vT[64*136];
  int bid = blockIdx.x;
  int c = bid & 31; int kvh = (bid >> 5) & 7; int b = bid >> 8;
  int tid = threadIdx.x, lane = tid & 63, w = tid >> 6, lr = lane & 15, lg = lane >> 4;
  int s0 = c*128;
  const unsigned short* kp = ktr + ((size_t)(b*gKVH+kvh)*64)*gS;
  const unsigned short* vp = vt  + ((size_t)(b*gKVH+kvh)*64)*gS;
  #pragma unroll
  for (int i = 0; i < 4; ++i){
    int cc = tid + 256*i; int d = cc >> 4, ch = cc & 15;
    unsigned short t[8]; unpack8(*(const uint4*)&kp[(size_t)d*gS + s0 + ch*8], t);
    #pragma unroll
    for (int u = 0; u < 8; ++u) t[u] = f2bf(phi_f(bf2f(t[u])));
    *(uint4*)&pkT[d*136 + ch*8] = pack8(t);
    *(uint4*)&vT[d*136 + ch*8]  = *(const uint4*)&vp[(size_t)d*gS + s0 + ch*8];
  }
  __syncthreads();
  f32x4 acc[4] = {};
  #pragma unroll
  for (int kk = 0; kk < 128; kk += 32){
    bf16x8 a = *(const bf16x8*)&pkT[(16*w+lr)*136 + kk + 8*lg];
    #pragma unroll
    for (int et = 0; et < 4; ++et){
      bf16x8 bv = *(const bf16x8*)&vT[(16*et+lr)*136 + kk + 8*lg];
      acc[et] = __builtin_amdgcn_mfma_f32_16x16x32_bf16(a, bv, acc[et], 0, 0, 0);
    }
  }
  size_t base = (size_t)((b*gKVH+kvh)*gNC + c);
  float* kvp = kvbuf + base*4096;
  #pragma unroll
  for (int et = 0; et < 4; ++et)
    #pragma unroll
    for (int r = 0; r < 4; ++r)
      kvp[(16*w + 4*lg + r)*64 + 16*et + lr] = acc[et][r];   // d-major [d][e]
  if (tid < 64){
    float sum = 0.f;
    for (int k = 0; k < 128; ++k) sum += bf2f(pkT[tid*136 + k]);
    ksbuf[base*64 + tid] = sum;
  }
}

// ---------------- linear attention pass 2: exclusive scan; kv transposed to e-major ----------------
__global__ void lin_pass2(const float* __restrict__ kvin, float* __restrict__ kvout,
                          float* __restrict__ ksbuf){
  int t = blockIdx.x*256 + threadIdx.x;
  const int per = 4096 + 64;
  if (t >= gB*gKVH*per) return;
  int bh = t / per; int e = t % per;
  if (e < 4096){
    int d = e >> 6, ecol = e & 63;
    const float* p = kvin  + (size_t)bh*gNC*4096 + e;
    float* q       = kvout + (size_t)bh*gNC*4096 + ecol*64 + d;
    float acc = 0.f;
    for (int cix = 0; cix < gNC; ++cix){ float v = p[(size_t)cix*4096]; q[(size_t)cix*4096] = acc; acc += v; }
  } else {
    float* p = ksbuf + (size_t)bh*gNC*64 + (e - 4096);
    float acc = 0.f;
    for (int cix = 0; cix < gNC; ++cix){ float v = p[cix*64]; p[cix*64] = acc; acc += v; }
  }
}

// ---------------- linear attention pass 3 ----------------
__global__ __launch_bounds__(256) void lin_pass3(const unsigned short* __restrict__ q_r,
                                                 const unsigned short* __restrict__ k_r,
                                                 const unsigned short* __restrict__ vt,
                                                 const float* __restrict__ SprevT,
                                                 const float* __restrict__ zprev,
                                                 unsigned short* __restrict__ olin)
{
  __shared__ unsigned short pq[128*72];
  __shared__ unsigned short pk[64*72];
  __shared__ unsigned short Ph[128*72];
  __shared__ unsigned short vT[64*72];
  __shared__ unsigned short SpT[64*72];
  __shared__ float zp[64];

  int bid = blockIdx.x;
  int c = bid & 31; int h = (bid >> 5) & 31; int b = bid >> 10;
  int kvh = h >> 2;
  int tid = threadIdx.x, lane = tid & 63, w = tid >> 6, lr = lane & 15, lg = lane >> 4;
  int s0 = c*128;
  const unsigned short* qp = q_r + ((size_t)(b*gH  +h  )*gS + s0)*64;
  const unsigned short* kp = k_r + ((size_t)(b*gKVH+kvh)*gS + s0)*64;
  const unsigned short* vp = vt  + ((size_t)(b*gKVH+kvh)*64)*gS;
  const float* Sp  = SprevT + ((size_t)((b*gKVH+kvh)*gNC + c))*4096;
  const float* zpg = zprev  + ((size_t)((b*gKVH+kvh)*gNC + c))*64;

  #pragma unroll
  for (int i = 0; i < 4; ++i){
    int cc = tid + 256*i; int row = cc >> 3, d0 = (cc & 7)*8;
    unsigned short t[8]; unpack8(*(const uint4*)(qp + row*64 + d0), t);
    #pragma unroll
    for (int u = 0; u < 8; ++u) pq[row*72 + d0 + u] = f2bf(phi_f(bf2f(t[u])));
  }
  #pragma unroll
  for (int i = 0; i < 16; ++i){
    int f = tid + 256*i; int e = f >> 6, d = f & 63;
    SpT[e*72 + d] = f2bf(Sp[f]);
  }
  if (tid < 64) zp[tid] = zpg[tid];

  float den[2][4] = {};
  f32x4 accO[2][4] = {};

  for (int kh = 0; kh < 2; ++kh){
    __syncthreads();
    #pragma unroll
    for (int i = 0; i < 2; ++i){
      int cc = tid + 256*i; int kr = cc >> 3, d0 = (cc & 7)*8;
      unsigned short t[8]; unpack8(*(const uint4*)(kp + (kh*64+kr)*64 + d0), t);
      #pragma unroll
      for (int u = 0; u < 8; ++u) pk[kr*72 + d0 + u] = f2bf(phi_f(bf2f(t[u])));
      *(uint4*)&vT[kr*72 + d0] = *(const uint4*)&vp[(size_t)kr*gS + s0 + kh*64 + d0];
    }
    __syncthreads();

    f32x4 sc[2][4] = {};
    #pragma unroll
    for (int kk = 0; kk < 64; kk += 32){
      bf16x8 a[2];
      #pragma unroll
      for (int rt = 0; rt < 2; ++rt) a[rt] = *(const bf16x8*)&pq[(32*w+16*rt+lr)*72 + kk + 8*lg];
      #pragma unroll
      for (int ct = 0; ct < 4; ++ct){
        bf16x8 bk = *(const bf16x8*)&pk[(16*ct+lr)*72 + kk + 8*lg];
        #pragma unroll
        for (int rt = 0; rt < 2; ++rt)
          sc[rt][ct] = __builtin_amdgcn_mfma_f32_16x16x32_bf16(a[rt], bk, sc[rt][ct], 0, 0, 0);
      }
    }
    #pragma unroll
    for (int rt = 0; rt < 2; ++rt)
      #pragma unroll
      for (int ct = 0; ct < 4; ++ct)
        #pragma unroll
        for (int r = 0; r < 4; ++r){
          int qrow = 32*w + 16*rt + 4*lg + r;
          int krow = kh*64 + 16*ct + lr;
          float sv = (krow <= qrow) ? sc[rt][ct][r] : 0.f;
          den[rt][r] += sv;
          Ph[qrow*72 + 16*ct + lr] = f2bf(sv);
        }
    #pragma unroll
    for (int kk = 0; kk < 64; kk += 32){
      bf16x8 ap[2];
      #pragma unroll
      for (int rt = 0; rt < 2; ++rt) ap[rt] = *(const bf16x8*)&Ph[(32*w+16*rt+lr)*72 + kk + 8*lg];
      #pragma unroll
      for (int et = 0; et < 4; ++et){
        bf16x8 bv = *(const bf16x8*)&vT[(16*et+lr)*72 + kk + 8*lg];
        #pragma unroll
        for (int rt = 0; rt < 2; ++rt)
          accO[rt][et] = __builtin_amdgcn_mfma_f32_16x16x32_bf16(ap[rt], bv, accO[rt][et], 0, 0, 0);
      }
    }
  }
  #pragma unroll
  for (int kk = 0; kk < 64; kk += 32){
    bf16x8 a[2];
    #pragma unroll
    for (int rt = 0; rt < 2; ++rt) a[rt] = *(const bf16x8*)&pq[(32*w+16*rt+lr)*72 + kk + 8*lg];
    #pragma unroll
    for (int et = 0; et < 4; ++et){
      bf16x8 bs = *(const bf16x8*)&SpT[(16*et+lr)*72 + kk + 8*lg];
      #pragma unroll
      for (int rt = 0; rt < 2; ++rt)
        accO[rt][et] = __builtin_amdgcn_mfma_f32_16x16x32_bf16(a[rt], bs, accO[rt][et], 0, 0, 0);
    }
  }
  #pragma unroll
  for (int rt = 0; rt < 2; ++rt)
    #pragma unroll
    for (int r = 0; r < 4; ++r){
      int qrow = 32*w + 16*rt + 4*lg + r;
      float part = 0.f;
      #pragma unroll
      for (int u = 0; u < 4; ++u){
        int d = 4*lr + u;
        part += bf2f(pq[qrow*72 + d]) * zp[d];
      }
      den[rt][r] += part;
      #pragma unroll
      for (int off = 1; off < 16; off <<= 1)
        den[rt][r] += __shfl_xor(den[rt][r], off);
    }
  #pragma unroll
  for (int rt = 0; rt < 2; ++rt)
    #pragma unroll
    for (int et = 0; et < 4; ++et)
      #pragma unroll
      for (int r = 0; r < 4; ++r){
        int qrow = 32*w + 16*rt + 4*lg + r;
        int e = 16*et + lr;
        float o = accO[rt][et][r] / (den[rt][r] + 1e-6f);
        int s = s0 + qrow;
        olin[((size_t)(b*gS+s)*gH + h)*64 + e] = f2bf(0.5f * o);
      }
}

// ---------------- host launch ----------------
extern "C" void kernel_launch(void* const* d_in, const int* in_sizes, int n_in,
                              void* d_out, int out_size, void* d_ws, size_t ws_size,
                              hipStream_t stream)
{
  const float* hidden = (const float*)d_in[0];
  const float* cosb   = (const float*)d_in[1];
  const float* sinb   = (const float*)d_in[2];
  const float* Wq     = (const float*)d_in[3];
  const float* Wk     = (const float*)d_in[4];
  const float* Wv     = (const float*)d_in[5];
  const float* Wo     = (const float*)d_in[6];
  float* out = (float*)d_out;

  char* ws = (char*)d_ws;
  size_t off = 0;
  auto alloc = [&](size_t bytes)->void*{
    void* p = ws + off; off += (bytes + 255) & ~(size_t)255; return p;
  };
  unsigned short* hbf    = (unsigned short*)alloc((size_t)gBS*gHID*2);   // hidden bf16; reused as hybrid bf16
  unsigned short* wqkv   = (unsigned short*)alloc((size_t)3072*gHID*2);  // [Wq;Wk;Wv]
  unsigned short* wob    = (unsigned short*)alloc((size_t)gHID*gHID*2);
  unsigned short* qkv    = (unsigned short*)alloc((size_t)gBS*3072*2);   // (B,S,[q|k|v])
  unsigned short* q_r    = (unsigned short*)alloc((size_t)gBS*gHID*2);   // (B,H,S,64)
  unsigned short* k_r    = (unsigned short*)alloc((size_t)gBS*512*2);    // (B,KVH,S,64)
  unsigned short* ktr    = (unsigned short*)alloc((size_t)gBS*512*2);    // (B,KVH,64,S)
  unsigned short* vt     = (unsigned short*)alloc((size_t)gBS*512*2);    // (B,KVH,64,S)
  unsigned short* olocal = (unsigned short*)alloc((size_t)gBS*gHID*2);
  unsigned short* olin   = (unsigned short*)alloc((size_t)gBS*gHID*2);
  float* kvbuf           = (float*)alloc((size_t)gB*gKVH*gNC*4096*4);
  float* kvT             = (float*)alloc((size_t)gB*gKVH*gNC*4096*4);
  float* ksbuf           = (float*)alloc((size_t)gB*gKVH*gNC*64*4);

  auto cvt = [&](const float* in, unsigned short* o, int n){
    int nb = (n/4 + 255)/256; if (nb > 4096) nb = 4096;
    cvt_kernel<<<dim3(nb), dim3(256), 0, stream>>>(in, o, n);
  };
  cvt(hidden, hbf, gBS*gHID);
  cvt(Wq, wqkv, gHID*gHID);
  cvt(Wk, wqkv + (size_t)2048*gHID, 512*gHID);
  cvt(Wv, wqkv + (size_t)2560*gHID, 512*gHID);
  cvt(Wo, wob, gHID*gHID);

  gemm128<1><<<dim3(64*12), dim3(512), 0, stream>>>(hbf, wqkv, (void*)qkv, 8192, 3072, 2048);

  rope_kernel<<<dim3((gB*gS*gH*4)/256),   dim3(256), 0, stream>>>(qkv,        cosb, sinb, q_r, gH,   3072);
  rope_kernel<<<dim3((gB*gS*gKVH*4)/256), dim3(256), 0, stream>>>(qkv + 2048, cosb, sinb, k_r, gKVH, 3072);

  transpose64<<<dim3(gB*gKVH*64), dim3(256), 0, stream>>>(k_r, ktr, 64,   0,    0);
  transpose64<<<dim3(gB*gKVH*64), dim3(256), 0, stream>>>(qkv, vt,  3072, 2560, 1);

  local_attn<<<dim3(gB*gH*64), dim3(256), 0, stream>>>(q_r, k_r, vt, olocal);
  lin_pass1<<<dim3(gB*gKVH*gNC), dim3(256), 0, stream>>>(ktr, vt, kvbuf, ksbuf);
  lin_pass2<<<dim3((gB*gKVH*(4096+64) + 255)/256), dim3(256), 0, stream>>>(kvbuf, kvT, ksbuf);
  lin_pass3<<<dim3(gB*gH*gNC), dim3(256), 0, stream>>>(q_r, k_r, vt, kvT, ksbuf, olin);

  combine_kernel<<<dim3(gBS*gHID/8/256), dim3(256), 0, stream>>>(olocal, olin, hbf, gBS*gHID/8);
  gemm128<0><<<dim3(64*8), dim3(512), 0, stream>>>(hbf, wob, (void*)out, 8192, 2048, 2048);
}

// Round 5
// 415.743 us; speedup vs baseline: 1.2787x; 1.0147x over previous
//
#include <hip/hip_runtime.h>

// ---------------- problem constants ----------------
#define gB 2
#define gS 4096
#define gH 32
#define gKVH 8
#define gHID 2048
#define gNC 32            // S / CHK
#define gBS (gB*gS)       // 8192
// D = 64, WIN = 256, CHK = 128, NREP = 4 are hard-coded below.

using bf16x8 = __attribute__((ext_vector_type(8))) short;
using f32x4  = __attribute__((ext_vector_type(4))) float;

__device__ __forceinline__ float bf2f(unsigned short u){
  return __uint_as_float(((unsigned)u) << 16);
}
__device__ __forceinline__ unsigned short f2bf(float f){
  unsigned u = __float_as_uint(f);
  u = (u + 0x7fffu + ((u >> 16) & 1u)) >> 16;   // RNE
  return (unsigned short)u;
}
__device__ __forceinline__ float phi_f(float x){ return x > 0.f ? x + 1.f : __expf(x); } // elu(x)+1

__device__ __forceinline__ void unpack8(uint4 v, unsigned short* o){
  o[0]=(unsigned short)(v.x&0xffffu); o[1]=(unsigned short)(v.x>>16);
  o[2]=(unsigned short)(v.y&0xffffu); o[3]=(unsigned short)(v.y>>16);
  o[4]=(unsigned short)(v.z&0xffffu); o[5]=(unsigned short)(v.z>>16);
  o[6]=(unsigned short)(v.w&0xffffu); o[7]=(unsigned short)(v.w>>16);
}
__device__ __forceinline__ uint4 pack8(const unsigned short* s){
  uint4 v;
  v.x = (unsigned)s[0] | ((unsigned)s[1]<<16);
  v.y = (unsigned)s[2] | ((unsigned)s[3]<<16);
  v.z = (unsigned)s[4] | ((unsigned)s[5]<<16);
  v.w = (unsigned)s[6] | ((unsigned)s[7]<<16);
  return v;
}

// async global->LDS, 16B per lane; LDS dest = wave-uniform base + lane*16
typedef const __attribute__((address_space(1))) void* gas_ptr;
typedef __attribute__((address_space(3))) void* las_ptr;
__device__ __forceinline__ void gload16(const void* g, void* l){
  __builtin_amdgcn_global_load_lds((gas_ptr)g, (las_ptr)l, 16, 0, 0);
}

// ---------------- f32 -> bf16 convert ----------------
__global__ void cvt_kernel(const float* __restrict__ in, unsigned short* __restrict__ out, int n){
  int stride = gridDim.x * blockDim.x;
  for (int i = blockIdx.x*blockDim.x + threadIdx.x; i*4 < n; i += stride){
    float4 v = *(const float4*)(in + (size_t)i*4);
    ushort4 o;
    o.x = f2bf(v.x); o.y = f2bf(v.y); o.z = f2bf(v.z); o.w = f2bf(v.w);
    *(ushort4*)(out + (size_t)i*4) = o;
  }
}

// ---------------- combine two bf16 buffers (a+b) -> bf16 ----------------
__global__ void combine_kernel(const unsigned short* __restrict__ a,
                               const unsigned short* __restrict__ b,
                               unsigned short* __restrict__ o, int n8){
  int i = blockIdx.x*256 + threadIdx.x;
  if (i >= n8) return;
  uint4 va = ((const uint4*)a)[i], vb = ((const uint4*)b)[i];
  unsigned short ta[8], tb[8], to[8];
  unpack8(va, ta); unpack8(vb, tb);
  #pragma unroll
  for (int u = 0; u < 8; ++u) to[u] = f2bf(bf2f(ta[u]) + bf2f(tb[u]));
  ((uint4*)o)[i] = pack8(to);
}

// ---------------- GEMM 256x256 deep pipeline: C[M,N] = A[M,K] * B[N,K]^T ----------------
// 8 waves (2M x 4N), per-wave 128x64 output (8x4 frags of 16x16x32 bf16, 2.67 MFMA/ds_read).
// BK=32, 4 LDS buffers of 32KB (A 256x32 + B 256x32) = 128 KiB, prefetch depth 3.
// One barrier per K-tile; counted vmcnt (4 loads/thread/tile, steady wait = 8);
// tail iterations use vmcnt(4)/vmcnt(0). setprio around the MFMA cluster.
// Both-sides XOR swizzle (granule ^= (row>>1)&3) -> bank-conflict-free ds_read_b128.
// Ledger: stage(t+3) issued AFTER barrier of tile t, into buf (t+3)&3 = (t-1)&3,
// whose readers all passed that barrier. vmcnt(8)+barrier => tile t fully landed.
template<int OUT_BF16>
__global__ __launch_bounds__(512, 2) void gemm256(const unsigned short* __restrict__ A,
                                                  const unsigned short* __restrict__ Bm,
                                                  void* __restrict__ Cout,
                                                  int Mdim, int Ndim, int Kdim)
{
  __shared__ unsigned short Sh[4*16384];   // buf s: A at s*16384 (256x32), B at +8192
  int tid = threadIdx.x, lane = tid & 63, w = tid >> 6, lr = lane & 15, lg = lane >> 4;
  int wm = w >> 2, wn = w & 3;
  int ntn = Ndim >> 8;
  int nwg = gridDim.x;
  int bid = (int)blockIdx.x;
  int swz = (bid & 7) * (nwg >> 3) + (bid >> 3);   // XCD-chunked (nwg % 8 == 0)
  long m0 = (long)(swz / ntn) * 256;
  long n0 = (long)(swz % ntn) * 256;
  int NT = Kdim >> 5;

  f32x4 acc[8][4] = {};

  auto stage = [&](int t){
    int sbase = (t & 3) * 16384;
    int k0 = t << 5;
    #pragma unroll
    for (int i = 0; i < 2; ++i){
      int c = w*64 + lane + i*512;             // chunk 0..1023 (256 rows x 4)
      int row = c >> 2;
      int colb = ((c & 3) << 4) ^ (((row >> 1) & 3) << 4);
      gload16((const char*)A + ((m0 + row) * (long)Kdim + k0) * 2 + colb,
              (void*)&Sh[sbase + (w*64 + i*512)*8]);
      gload16((const char*)Bm + ((n0 + row) * (long)Kdim + k0) * 2 + colb,
              (void*)&Sh[sbase + 8192 + (w*64 + i*512)*8]);
    }
  };

  auto body = [&](int t){
    int sb = (t & 3) * 16384;
    __builtin_amdgcn_s_barrier();
    if (t + 3 < NT) stage(t + 3);
    bf16x8 af[8], bfr[4];
    #pragma unroll
    for (int m = 0; m < 8; ++m){
      int row = wm*128 + m*16 + lr;
      af[m] = *(const bf16x8*)&Sh[sb + row*32 + ((lg ^ ((row >> 1) & 3)) << 3)];
    }
    #pragma unroll
    for (int n = 0; n < 4; ++n){
      int row = wn*64 + n*16 + lr;
      bfr[n] = *(const bf16x8*)&Sh[sb + 8192 + row*32 + ((lg ^ ((row >> 1) & 3)) << 3)];
    }
    __builtin_amdgcn_s_setprio(1);
    #pragma unroll
    for (int m = 0; m < 8; ++m)
      #pragma unroll
      for (int n = 0; n < 4; ++n)
        acc[m][n] = __builtin_amdgcn_mfma_f32_16x16x32_bf16(af[m], bfr[n], acc[m][n], 0, 0, 0);
    __builtin_amdgcn_s_setprio(0);
  };

  // prologue: tiles 0..2 in flight (12 loads/thread)
  stage(0); stage(1); stage(2);
  for (int t = 0; t < NT - 2; ++t){
    asm volatile("s_waitcnt vmcnt(8)" ::: "memory");
    body(t);
  }
  asm volatile("s_waitcnt vmcnt(4)" ::: "memory");
  body(NT - 2);
  asm volatile("s_waitcnt vmcnt(0)" ::: "memory");
  body(NT - 1);

  // epilogue: C/D layout col = lane&15, row = 4*(lane>>4) + reg
  #pragma unroll
  for (int m = 0; m < 8; ++m)
    #pragma unroll
    for (int n = 0; n < 4; ++n)
      #pragma unroll
      for (int r = 0; r < 4; ++r){
        long row = m0 + wm*128 + m*16 + 4*lg + r;
        long col = n0 + wn*64 + n*16 + lr;
        float v = acc[m][n][r];
        if (OUT_BF16) ((unsigned short*)Cout)[row*Ndim + col] = f2bf(v);
        else          ((float*)Cout)[row*Ndim + col] = v;
      }
}

// ---------------- RoPE + transpose -> (B,Hx,S,64), bf16 ----------------
__global__ void rope_kernel(const unsigned short* __restrict__ in, const float* __restrict__ cosb,
                            const float* __restrict__ sinb, unsigned short* __restrict__ out,
                            int Hx, int tokstride)
{
  int idx = blockIdx.x*256 + threadIdx.x;
  int total = gB*gS*Hx*4;
  if (idx >= total) return;
  int dq = idx & 3; int h = (idx >> 2) % Hx; int rem = idx / (4*Hx);
  int s = rem % gS; int b = rem / gS;
  int dp = dq*8;
  const unsigned short* ip = in + (size_t)(b*gS+s)*tokstride + h*64;
  unsigned short xlo[8], xhi[8], olo[8], ohi[8];
  unpack8(*(const uint4*)(ip + dp), xlo);
  unpack8(*(const uint4*)(ip + dp + 32), xhi);
  const float* cp = cosb + (size_t)(b*gS+s)*64;
  const float* sp = sinb + (size_t)(b*gS+s)*64;
  #pragma unroll
  for (int u = 0; u < 8; ++u){
    float x1 = bf2f(xlo[u]), x2 = bf2f(xhi[u]);
    float c1 = cp[dp+u], s1 = sp[dp+u], c2 = cp[dp+32+u], s2 = sp[dp+32+u];
    olo[u] = f2bf(x1*c1 - x2*s1);
    ohi[u] = f2bf(x2*c2 + x1*s2);
  }
  unsigned short* op = out + ((size_t)(b*Hx+h)*gS + s)*64;
  *(uint4*)(op + dp)      = pack8(olo);
  *(uint4*)(op + dp + 32) = pack8(ohi);
}

// ---------------- 64x64 tile transpose -> d-major (B,KVH,64,S) ----------------
// mode 0: in = (B,KVH,S,64) rows (k_r).  mode 1: in = fused proj (B,S,tokStride), slice at +voff.
__global__ __launch_bounds__(256) void transpose64(const unsigned short* __restrict__ in,
                                                   unsigned short* __restrict__ out,
                                                   int tokStride, int voff, int mode)
{
  __shared__ unsigned short T[64*72];
  int bid = blockIdx.x;
  int st = bid & 63; int kvh = (bid >> 6) & 7; int b = bid >> 9;
  int s0 = st*64;
  int tid = threadIdx.x;
  const unsigned short* ip;
  size_t tokstr;
  if (mode == 0){ ip = in + ((size_t)(b*gKVH+kvh)*gS + s0)*64;                  tokstr = 64; }
  else          { ip = in + (size_t)(b*gS+s0)*tokStride + voff + kvh*64;        tokstr = tokStride; }
  #pragma unroll
  for (int i = 0; i < 2; ++i){
    int cc = tid + 256*i; int sl = cc >> 3, ch = cc & 7;
    *(uint4*)&T[sl*72 + ch*8] = *(const uint4*)&ip[(size_t)sl*tokstr + ch*8];
  }
  __syncthreads();
  unsigned short* op = out + ((size_t)(b*gKVH+kvh)*64)*gS;
  #pragma unroll
  for (int i = 0; i < 2; ++i){
    int cc = tid + 256*i; int d = cc >> 3, ch = cc & 7;
    unsigned short t[8];
    #pragma unroll
    for (int u = 0; u < 8; ++u) t[u] = T[(ch*8+u)*72 + d];
    *(uint4*)&op[(size_t)d*gS + s0 + ch*8] = pack8(t);
  }
}

// ---------------- local sliding-window attention ----------------
__global__ __launch_bounds__(256) void local_attn(const unsigned short* __restrict__ q_r,
                                                  const unsigned short* __restrict__ k_r,
                                                  const unsigned short* __restrict__ vt,
                                                  unsigned short* __restrict__ olocal)
{
  __shared__ unsigned short Qs[64*72];
  __shared__ unsigned short Ks[64*72];
  __shared__ unsigned short VTs[64*72];
  __shared__ unsigned short Ps[4*16*72];
  int bid = blockIdx.x;
  int qt = bid & 63; int h = (bid >> 6) & 31; int b = bid >> 11;
  int kvh = h >> 2;
  int q0 = qt*64;
  int tid = threadIdx.x, lane = tid & 63, w = tid >> 6, lr = lane & 15, lg = lane >> 4;
  const unsigned short* qp = q_r + ((size_t)(b*gH  +h  )*gS + q0)*64;
  const unsigned short* kp = k_r + ((size_t)(b*gKVH+kvh)*gS)*64;
  const unsigned short* vp = vt  + ((size_t)(b*gKVH+kvh)*64)*gS;   // rows d, stride S

  #pragma unroll
  for (int i = 0; i < 2; ++i){
    int cc = tid + 256*i; int row = cc >> 3, ch = cc & 7;
    *(uint4*)&Qs[row*72 + ch*8] = *(const uint4*)&qp[row*64 + ch*8];
  }
  float mrun[4], lsum[4];
  f32x4 accO[4] = {};
  #pragma unroll
  for (int r = 0; r < 4; ++r){ mrun[r] = -1e30f; lsum[r] = 0.f; }
  int wq = w*16;
  int kt0 = (q0 >= 256) ? 0 : ((256 - q0) >> 6);

  for (int kt = kt0; kt < 5; ++kt){
    int kb = q0 - 256 + kt*64;
    __syncthreads();
    #pragma unroll
    for (int i = 0; i < 2; ++i){
      int cc = tid + 256*i; int row = cc >> 3, ch = cc & 7;
      *(uint4*)&Ks[row*72 + ch*8]  = *(const uint4*)&kp[(size_t)(kb+row)*64 + ch*8];
      *(uint4*)&VTs[row*72 + ch*8] = *(const uint4*)&vp[(size_t)row*gS + kb + ch*8];
    }
    __syncthreads();

    f32x4 sc[4] = {};
    #pragma unroll
    for (int kk = 0; kk < 64; kk += 32){
      bf16x8 aq = *(const bf16x8*)&Qs[(wq+lr)*72 + kk + 8*lg];
      #pragma unroll
      for (int f = 0; f < 4; ++f){
        bf16x8 bk = *(const bf16x8*)&Ks[(f*16+lr)*72 + kk + 8*lg];
        sc[f] = __builtin_amdgcn_mfma_f32_16x16x32_bf16(aq, bk, sc[f], 0, 0, 0);
      }
    }
    float rmax[4]; bool keepM[4][4];
    #pragma unroll
    for (int r = 0; r < 4; ++r) rmax[r] = -1e30f;
    #pragma unroll
    for (int f = 0; f < 4; ++f)
      #pragma unroll
      for (int r = 0; r < 4; ++r){
        int i = wq + 4*lg + r;
        int j = kt*64 + f*16 + lr;
        bool keep = (j > i) && (j <= i + 256);
        keepM[f][r] = keep;
        float s = sc[f][r]*0.125f;
        s = keep ? s : -1e30f;
        sc[f][r] = s;
        rmax[r] = fmaxf(rmax[r], s);
      }
    #pragma unroll
    for (int off = 1; off < 16; off <<= 1)
      #pragma unroll
      for (int r = 0; r < 4; ++r) rmax[r] = fmaxf(rmax[r], __shfl_xor(rmax[r], off));
    float psum[4];
    #pragma unroll
    for (int r = 0; r < 4; ++r){
      float mn = fmaxf(mrun[r], rmax[r]);
      float al = __expf(mrun[r] - mn);
      mrun[r] = mn;
      lsum[r] *= al;
      #pragma unroll
      for (int dt = 0; dt < 4; ++dt) accO[dt][r] *= al;
      psum[r] = 0.f;
    }
    #pragma unroll
    for (int f = 0; f < 4; ++f)
      #pragma unroll
      for (int r = 0; r < 4; ++r){
        float p = keepM[f][r] ? __expf(sc[f][r] - mrun[r]) : 0.f;
        psum[r] += p;
        Ps[w*1152 + (4*lg + r)*72 + f*16 + lr] = f2bf(p);
      }
    #pragma unroll
    for (int off = 1; off < 16; off <<= 1)
      #pragma unroll
      for (int r = 0; r < 4; ++r) psum[r] += __shfl_xor(psum[r], off);
    #pragma unroll
    for (int r = 0; r < 4; ++r) lsum[r] += psum[r];
    // Ps write->read is same-wave LDS (in-order DS pipe) — no barrier needed.
    #pragma unroll
    for (int kk = 0; kk < 64; kk += 32){
      bf16x8 ap = *(const bf16x8*)&Ps[w*1152 + lr*72 + kk + 8*lg];
      #pragma unroll
      for (int dt = 0; dt < 4; ++dt){
        bf16x8 bv = *(const bf16x8*)&VTs[(dt*16+lr)*72 + kk + 8*lg];
        accO[dt] = __builtin_amdgcn_mfma_f32_16x16x32_bf16(ap, bv, accO[dt], 0, 0, 0);
      }
    }
  }
  #pragma unroll
  for (int dt = 0; dt < 4; ++dt)
    #pragma unroll
    for (int r = 0; r < 4; ++r){
      int s = q0 + wq + 4*lg + r;
      int d = dt*16 + lr;
      float o = accO[dt][r] / lsum[r];
      olocal[((size_t)(b*gS+s)*gH + h)*64 + d] = f2bf(0.5f * o);
    }
}

// ---------------- linear attention pass 1 ----------------
__global__ __launch_bounds__(256) void lin_pass1(const unsigned short* __restrict__ ktr,
                                                 const unsigned short* __restrict__ vt,
                                                 float* __restrict__ kvbuf, float* __restrict__ ksbuf)
{
  __shared__ unsigned short pkT[64*136];
  __shared__ unsigned short vT[64*136];
  int bid = blockIdx.x;
  int c = bid & 31; int kvh = (bid >> 5) & 7; int b = bid >> 8;
  int tid = threadIdx.x, lane = tid & 63, w = tid >> 6, lr = lane & 15, lg = lane >> 4;
  int s0 = c*128;
  const unsigned short* kp = ktr + ((size_t)(b*gKVH+kvh)*64)*gS;
  const unsigned short* vp = vt  + ((size_t)(b*gKVH+kvh)*64)*gS;
  #pragma unroll
  for (int i = 0; i < 4; ++i){
    int cc = tid + 256*i; int d = cc >> 4, ch = cc & 15;
    unsigned short t[8]; unpack8(*(const uint4*)&kp[(size_t)d*gS + s0 + ch*8], t);
    #pragma unroll
    for (int u = 0; u < 8; ++u) t[u] = f2bf(phi_f(bf2f(t[u])));
    *(uint4*)&pkT[d*136 + ch*8] = pack8(t);
    *(uint4*)&vT[d*136 + ch*8]  = *(const uint4*)&vp[(size_t)d*gS + s0 + ch*8];
  }
  __syncthreads();
  f32x4 acc[4] = {};
  #pragma unroll
  for (int kk = 0; kk < 128; kk += 32){
    bf16x8 a = *(const bf16x8*)&pkT[(16*w+lr)*136 + kk + 8*lg];
    #pragma unroll
    for (int et = 0; et < 4; ++et){
      bf16x8 bv = *(const bf16x8*)&vT[(16*et+lr)*136 + kk + 8*lg];
      acc[et] = __builtin_amdgcn_mfma_f32_16x16x32_bf16(a, bv, acc[et], 0, 0, 0);
    }
  }
  size_t base = (size_t)((b*gKVH+kvh)*gNC + c);
  float* kvp = kvbuf + base*4096;
  #pragma unroll
  for (int et = 0; et < 4; ++et)
    #pragma unroll
    for (int r = 0; r < 4; ++r)
      kvp[(16*w + 4*lg + r)*64 + 16*et + lr] = acc[et][r];   // d-major [d][e]
  if (tid < 64){
    float sum = 0.f;
    for (int k = 0; k < 128; ++k) sum += bf2f(pkT[tid*136 + k]);
    ksbuf[base*64 + tid] = sum;
  }
}

// ---------------- linear attention pass 2: exclusive scan; kv transposed to e-major ----------------
__global__ void lin_pass2(const float* __restrict__ kvin, float* __restrict__ kvout,
                          float* __restrict__ ksbuf){
  int t = blockIdx.x*256 + threadIdx.x;
  const int per = 4096 + 64;
  if (t >= gB*gKVH*per) return;
  int bh = t / per; int e = t % per;
  if (e < 4096){
    int d = e >> 6, ecol = e & 63;
    const float* p = kvin  + (size_t)bh*gNC*4096 + e;
    float* q       = kvout + (size_t)bh*gNC*4096 + ecol*64 + d;
    float acc = 0.f;
    for (int cix = 0; cix < gNC; ++cix){ float v = p[(size_t)cix*4096]; q[(size_t)cix*4096] = acc; acc += v; }
  } else {
    float* p = ksbuf + (size_t)bh*gNC*64 + (e - 4096);
    float acc = 0.f;
    for (int cix = 0; cix < gNC; ++cix){ float v = p[cix*64]; p[cix*64] = acc; acc += v; }
  }
}

// ---------------- linear attention pass 3 ----------------
__global__ __launch_bounds__(256) void lin_pass3(const unsigned short* __restrict__ q_r,
                                                 const unsigned short* __restrict__ k_r,
                                                 const unsigned short* __restrict__ vt,
                                                 const float* __restrict__ SprevT,
                                                 const float* __restrict__ zprev,
                                                 unsigned short* __restrict__ olin)
{
  __shared__ unsigned short pq[128*72];
  __shared__ unsigned short pk[64*72];
  __shared__ unsigned short Ph[128*72];
  __shared__ unsigned short vT[64*72];
  __shared__ unsigned short SpT[64*72];
  __shared__ float zp[64];

  int bid = blockIdx.x;
  int c = bid & 31; int h = (bid >> 5) & 31; int b = bid >> 10;
  int kvh = h >> 2;
  int tid = threadIdx.x, lane = tid & 63, w = tid >> 6, lr = lane & 15, lg = lane >> 4;
  int s0 = c*128;
  const unsigned short* qp = q_r + ((size_t)(b*gH  +h  )*gS + s0)*64;
  const unsigned short* kp = k_r + ((size_t)(b*gKVH+kvh)*gS + s0)*64;
  const unsigned short* vp = vt  + ((size_t)(b*gKVH+kvh)*64)*gS;
  const float* Sp  = SprevT + ((size_t)((b*gKVH+kvh)*gNC + c))*4096;
  const float* zpg = zprev  + ((size_t)((b*gKVH+kvh)*gNC + c))*64;

  #pragma unroll
  for (int i = 0; i < 4; ++i){
    int cc = tid + 256*i; int row = cc >> 3, d0 = (cc & 7)*8;
    unsigned short t[8]; unpack8(*(const uint4*)(qp + row*64 + d0), t);
    #pragma unroll
    for (int u = 0; u < 8; ++u) pq[row*72 + d0 + u] = f2bf(phi_f(bf2f(t[u])));
  }
  #pragma unroll
  for (int i = 0; i < 16; ++i){
    int f = tid + 256*i; int e = f >> 6, d = f & 63;
    SpT[e*72 + d] = f2bf(Sp[f]);
  }
  if (tid < 64) zp[tid] = zpg[tid];

  float den[2][4] = {};
  f32x4 accO[2][4] = {};

  for (int kh = 0; kh < 2; ++kh){
    __syncthreads();
    #pragma unroll
    for (int i = 0; i < 2; ++i){
      int cc = tid + 256*i; int kr = cc >> 3, d0 = (cc & 7)*8;
      unsigned short t[8]; unpack8(*(const uint4*)(kp + (kh*64+kr)*64 + d0), t);
      #pragma unroll
      for (int u = 0; u < 8; ++u) pk[kr*72 + d0 + u] = f2bf(phi_f(bf2f(t[u])));
      *(uint4*)&vT[kr*72 + d0] = *(const uint4*)&vp[(size_t)kr*gS + s0 + kh*64 + d0];
    }
    __syncthreads();

    f32x4 sc[2][4] = {};
    #pragma unroll
    for (int kk = 0; kk < 64; kk += 32){
      bf16x8 a[2];
      #pragma unroll
      for (int rt = 0; rt < 2; ++rt) a[rt] = *(const bf16x8*)&pq[(32*w+16*rt+lr)*72 + kk + 8*lg];
      #pragma unroll
      for (int ct = 0; ct < 4; ++ct){
        bf16x8 bk = *(const bf16x8*)&pk[(16*ct+lr)*72 + kk + 8*lg];
        #pragma unroll
        for (int rt = 0; rt < 2; ++rt)
          sc[rt][ct] = __builtin_amdgcn_mfma_f32_16x16x32_bf16(a[rt], bk, sc[rt][ct], 0, 0, 0);
      }
    }
    #pragma unroll
    for (int rt = 0; rt < 2; ++rt)
      #pragma unroll
      for (int ct = 0; ct < 4; ++ct)
        #pragma unroll
        for (int r = 0; r < 4; ++r){
          int qrow = 32*w + 16*rt + 4*lg + r;
          int krow = kh*64 + 16*ct + lr;
          float sv = (krow <= qrow) ? sc[rt][ct][r] : 0.f;
          den[rt][r] += sv;
          Ph[qrow*72 + 16*ct + lr] = f2bf(sv);
        }
    #pragma unroll
    for (int kk = 0; kk < 64; kk += 32){
      bf16x8 ap[2];
      #pragma unroll
      for (int rt = 0; rt < 2; ++rt) ap[rt] = *(const bf16x8*)&Ph[(32*w+16*rt+lr)*72 + kk + 8*lg];
      #pragma unroll
      for (int et = 0; et < 4; ++et){
        bf16x8 bv = *(const bf16x8*)&vT[(16*et+lr)*72 + kk + 8*lg];
        #pragma unroll
        for (int rt = 0; rt < 2; ++rt)
          accO[rt][et] = __builtin_amdgcn_mfma_f32_16x16x32_bf16(ap[rt], bv, accO[rt][et], 0, 0, 0);
      }
    }
  }
  #pragma unroll
  for (int kk = 0; kk < 64; kk += 32){
    bf16x8 a[2];
    #pragma unroll
    for (int rt = 0; rt < 2; ++rt) a[rt] = *(const bf16x8*)&pq[(32*w+16*rt+lr)*72 + kk + 8*lg];
    #pragma unroll
    for (int et = 0; et < 4; ++et){
      bf16x8 bs = *(const bf16x8*)&SpT[(16*et+lr)*72 + kk + 8*lg];
      #pragma unroll
      for (int rt = 0; rt < 2; ++rt)
        accO[rt][et] = __builtin_amdgcn_mfma_f32_16x16x32_bf16(a[rt], bs, accO[rt][et], 0, 0, 0);
    }
  }
  #pragma unroll
  for (int rt = 0; rt < 2; ++rt)
    #pragma unroll
    for (int r = 0; r < 4; ++r){
      int qrow = 32*w + 16*rt + 4*lg + r;
      float part = 0.f;
      #pragma unroll
      for (int u = 0; u < 4; ++u){
        int d = 4*lr + u;
        part += bf2f(pq[qrow*72 + d]) * zp[d];
      }
      den[rt][r] += part;
      #pragma unroll
      for (int off = 1; off < 16; off <<= 1)
        den[rt][r] += __shfl_xor(den[rt][r], off);
    }
  #pragma unroll
  for (int rt = 0; rt < 2; ++rt)
    #pragma unroll
    for (int et = 0; et < 4; ++et)
      #pragma unroll
      for (int r = 0; r < 4; ++r){
        int qrow = 32*w + 16*rt + 4*lg + r;
        int e = 16*et + lr;
        float o = accO[rt][et][r] / (den[rt][r] + 1e-6f);
        int s = s0 + qrow;
        olin[((size_t)(b*gS+s)*gH + h)*64 + e] = f2bf(0.5f * o);
      }
}

// ---------------- host launch ----------------
extern "C" void kernel_launch(void* const* d_in, const int* in_sizes, int n_in,
                              void* d_out, int out_size, void* d_ws, size_t ws_size,
                              hipStream_t stream)
{
  const float* hidden = (const float*)d_in[0];
  const float* cosb   = (const float*)d_in[1];
  const float* sinb   = (const float*)d_in[2];
  const float* Wq     = (const float*)d_in[3];
  const float* Wk     = (const float*)d_in[4];
  const float* Wv     = (const float*)d_in[5];
  const float* Wo     = (const float*)d_in[6];
  float* out = (float*)d_out;

  char* ws = (char*)d_ws;
  size_t off = 0;
  auto alloc = [&](size_t bytes)->void*{
    void* p = ws + off; off += (bytes + 255) & ~(size_t)255; return p;
  };
  unsigned short* hbf    = (unsigned short*)alloc((size_t)gBS*gHID*2);   // hidden bf16; reused as hybrid bf16
  unsigned short* wqkv   = (unsigned short*)alloc((size_t)3072*gHID*2);  // [Wq;Wk;Wv]
  unsigned short* wob    = (unsigned short*)alloc((size_t)gHID*gHID*2);
  unsigned short* qkv    = (unsigned short*)alloc((size_t)gBS*3072*2);   // (B,S,[q|k|v])
  unsigned short* q_r    = (unsigned short*)alloc((size_t)gBS*gHID*2);   // (B,H,S,64)
  unsigned short* k_r    = (unsigned short*)alloc((size_t)gBS*512*2);    // (B,KVH,S,64)
  unsigned short* ktr    = (unsigned short*)alloc((size_t)gBS*512*2);    // (B,KVH,64,S)
  unsigned short* vt     = (unsigned short*)alloc((size_t)gBS*512*2);    // (B,KVH,64,S)
  unsigned short* olocal = (unsigned short*)alloc((size_t)gBS*gHID*2);
  unsigned short* olin   = (unsigned short*)alloc((size_t)gBS*gHID*2);
  float* kvbuf           = (float*)alloc((size_t)gB*gKVH*gNC*4096*4);
  float* kvT             = (float*)alloc((size_t)gB*gKVH*gNC*4096*4);
  float* ksbuf           = (float*)alloc((size_t)gB*gKVH*gNC*64*4);

  auto cvt = [&](const float* in, unsigned short* o, int n){
    int nb = (n/4 + 255)/256; if (nb > 4096) nb = 4096;
    cvt_kernel<<<dim3(nb), dim3(256), 0, stream>>>(in, o, n);
  };
  cvt(hidden, hbf, gBS*gHID);
  cvt(Wq, wqkv, gHID*gHID);
  cvt(Wk, wqkv + (size_t)2048*gHID, 512*gHID);
  cvt(Wv, wqkv + (size_t)2560*gHID, 512*gHID);
  cvt(Wo, wob, gHID*gHID);

  gemm256<1><<<dim3(32*12), dim3(512), 0, stream>>>(hbf, wqkv, (void*)qkv, 8192, 3072, 2048);

  rope_kernel<<<dim3((gB*gS*gH*4)/256),   dim3(256), 0, stream>>>(qkv,        cosb, sinb, q_r, gH,   3072);
  rope_kernel<<<dim3((gB*gS*gKVH*4)/256), dim3(256), 0, stream>>>(qkv + 2048, cosb, sinb, k_r, gKVH, 3072);

  transpose64<<<dim3(gB*gKVH*64), dim3(256), 0, stream>>>(k_r, ktr, 64,   0,    0);
  transpose64<<<dim3(gB*gKVH*64), dim3(256), 0, stream>>>(qkv, vt,  3072, 2560, 1);

  local_attn<<<dim3(gB*gH*64), dim3(256), 0, stream>>>(q_r, k_r, vt, olocal);
  lin_pass1<<<dim3(gB*gKVH*gNC), dim3(256), 0, stream>>>(ktr, vt, kvbuf, ksbuf);
  lin_pass2<<<dim3((gB*gKVH*(4096+64) + 255)/256), dim3(256), 0, stream>>>(kvbuf, kvT, ksbuf);
  lin_pass3<<<dim3(gB*gH*gNC), dim3(256), 0, stream>>>(q_r, k_r, vt, kvT, ksbuf, olin);

  combine_kernel<<<dim3(gBS*gHID/8/256), dim3(256), 0, stream>>>(olocal, olin, hbf, gBS*gHID/8);
  gemm256<0><<<dim3(32*8), dim3(512), 0, stream>>>(hbf, wob, (void*)out, 8192, 2048, 2048);
}

// Round 6
// 400.783 us; speedup vs baseline: 1.3264x; 1.0373x over previous
//
#include <hip/hip_runtime.h>

// ---------------- problem constants ----------------
#define gB 2
#define gS 4096
#define gH 32
#define gKVH 8
#define gHID 2048
#define gNC 32            // S / CHK
#define gBS (gB*gS)       // 8192
// D = 64, WIN = 256, CHK = 128, NREP = 4 are hard-coded below.

using bf16x8 = __attribute__((ext_vector_type(8))) short;
using f32x4  = __attribute__((ext_vector_type(4))) float;

__device__ __forceinline__ float bf2f(unsigned short u){
  return __uint_as_float(((unsigned)u) << 16);
}
__device__ __forceinline__ unsigned short f2bf(float f){
  unsigned u = __float_as_uint(f);
  u = (u + 0x7fffu + ((u >> 16) & 1u)) >> 16;   // RNE
  return (unsigned short)u;
}
__device__ __forceinline__ float phi_f(float x){ return x > 0.f ? x + 1.f : __expf(x); } // elu(x)+1

__device__ __forceinline__ void unpack8(uint4 v, unsigned short* o){
  o[0]=(unsigned short)(v.x&0xffffu); o[1]=(unsigned short)(v.x>>16);
  o[2]=(unsigned short)(v.y&0xffffu); o[3]=(unsigned short)(v.y>>16);
  o[4]=(unsigned short)(v.z&0xffffu); o[5]=(unsigned short)(v.z>>16);
  o[6]=(unsigned short)(v.w&0xffffu); o[7]=(unsigned short)(v.w>>16);
}
__device__ __forceinline__ uint4 pack8(const unsigned short* s){
  uint4 v;
  v.x = (unsigned)s[0] | ((unsigned)s[1]<<16);
  v.y = (unsigned)s[2] | ((unsigned)s[3]<<16);
  v.z = (unsigned)s[4] | ((unsigned)s[5]<<16);
  v.w = (unsigned)s[6] | ((unsigned)s[7]<<16);
  return v;
}

// async global->LDS, 16B per lane; LDS dest = wave-uniform base + lane*16
typedef const __attribute__((address_space(1))) void* gas_ptr;
typedef __attribute__((address_space(3))) void* las_ptr;
__device__ __forceinline__ void gload16(const void* g, void* l){
  __builtin_amdgcn_global_load_lds((gas_ptr)g, (las_ptr)l, 16, 0, 0);
}

// ---------------- f32 -> bf16 convert ----------------
__global__ void cvt_kernel(const float* __restrict__ in, unsigned short* __restrict__ out, int n){
  int stride = gridDim.x * blockDim.x;
  for (int i = blockIdx.x*blockDim.x + threadIdx.x; i*4 < n; i += stride){
    float4 v = *(const float4*)(in + (size_t)i*4);
    ushort4 o;
    o.x = f2bf(v.x); o.y = f2bf(v.y); o.z = f2bf(v.z); o.w = f2bf(v.w);
    *(ushort4*)(out + (size_t)i*4) = o;
  }
}

// ---------------- combine two bf16 buffers (a+b) -> bf16 ----------------
__global__ void combine_kernel(const unsigned short* __restrict__ a,
                               const unsigned short* __restrict__ b,
                               unsigned short* __restrict__ o, int n8){
  int i = blockIdx.x*256 + threadIdx.x;
  if (i >= n8) return;
  uint4 va = ((const uint4*)a)[i], vb = ((const uint4*)b)[i];
  unsigned short ta[8], tb[8], to[8];
  unpack8(va, ta); unpack8(vb, tb);
  #pragma unroll
  for (int u = 0; u < 8; ++u) to[u] = f2bf(bf2f(ta[u]) + bf2f(tb[u]));
  ((uint4*)o)[i] = pack8(to);
}

// ---------------- QKV GEMM 128x256 + fused RoPE/layout epilogue ----------------
// C[M,3072] = A[M,K] * Wqkv[3072,K]^T, round-4 pipeline (proven): BK=32, 4 LDS
// buffers of 24KB, depth-3 prefetch, 1 raw barrier/tile, counted vmcnt(6)/3/0,
// setprio MFMA, both-sides XOR swizzle. Wave tile 64x64 -> wave N-width is
// 64-aligned, so rope pair (d, d+32) = frags (n, n+2), same lane.
// Epilogue: block is entirely q (n0<2048), k (<2560) or v; writes
// q->q_r (B,H,S,64) roped, k->k_r (B,KVH,S,64) roped, v->vproj (B,S,512).
__global__ __launch_bounds__(512, 1) void gemm_qkv(const unsigned short* __restrict__ A,
                                                   const unsigned short* __restrict__ Bm,
                                                   const float* __restrict__ cosb,
                                                   const float* __restrict__ sinb,
                                                   unsigned short* __restrict__ q_r,
                                                   unsigned short* __restrict__ k_r,
                                                   unsigned short* __restrict__ vproj)
{
  const int Kdim = 2048;
  __shared__ unsigned short Sh[4*12288];   // buf s: A at s*12288 (128x32), B at +4096 (256x32)
  int tid = threadIdx.x, lane = tid & 63, w = tid >> 6, lr = lane & 15, lg = lane >> 4;
  int wm = w >> 2, wn = w & 3;
  const int ntn = 12;                      // 3072/256
  int nwg = gridDim.x;
  int bid = (int)blockIdx.x;
  int swz = (bid & 7) * (nwg >> 3) + (bid >> 3);   // XCD-chunked (nwg % 8 == 0)
  long m0 = (long)(swz / ntn) * 128;
  long n0 = (long)(swz % ntn) * 256;
  const int NT = Kdim >> 5;

  f32x4 acc[4][4] = {};

  auto stage = [&](int t){
    int sbase = (t & 3) * 12288;
    int k0 = t << 5;
    {
      int c = w*64 + lane;                     // chunk 0..511 (A: 128 rows x 4)
      int row = c >> 2;
      int colb = ((c & 3) << 4) ^ (((row >> 1) & 3) << 4);
      gload16((const char*)A + ((m0 + row) * (long)Kdim + k0) * 2 + colb,
              (void*)&Sh[sbase + w*512]);
    }
    #pragma unroll
    for (int i = 0; i < 2; ++i){
      int c = w*64 + lane + i*512;             // chunk 0..1023 (B: 256 rows x 4)
      int row = c >> 2;
      int colb = ((c & 3) << 4) ^ (((row >> 1) & 3) << 4);
      gload16((const char*)Bm + ((n0 + row) * (long)Kdim + k0) * 2 + colb,
              (void*)&Sh[sbase + 4096 + w*512 + i*4096]);
    }
  };

  auto body = [&](int t){
    int sb = (t & 3) * 12288;
    __builtin_amdgcn_s_barrier();
    if (t + 3 < NT) stage(t + 3);
    bf16x8 af[4], bfr[4];
    #pragma unroll
    for (int m = 0; m < 4; ++m){
      int row = wm*64 + m*16 + lr;
      af[m] = *(const bf16x8*)&Sh[sb + row*32 + ((lg ^ ((row >> 1) & 3)) << 3)];
    }
    #pragma unroll
    for (int n = 0; n < 4; ++n){
      int row = wn*64 + n*16 + lr;
      bfr[n] = *(const bf16x8*)&Sh[sb + 4096 + row*32 + ((lg ^ ((row >> 1) & 3)) << 3)];
    }
    __builtin_amdgcn_s_setprio(1);
    #pragma unroll
    for (int m = 0; m < 4; ++m)
      #pragma unroll
      for (int n = 0; n < 4; ++n)
        acc[m][n] = __builtin_amdgcn_mfma_f32_16x16x32_bf16(af[m], bfr[n], acc[m][n], 0, 0, 0);
    __builtin_amdgcn_s_setprio(0);
  };

  // prologue: tiles 0..2 in flight (9 loads/thread)
  stage(0); stage(1); stage(2);
  for (int t = 0; t < NT - 2; ++t){
    asm volatile("s_waitcnt vmcnt(6)" ::: "memory");
    body(t);
  }
  asm volatile("s_waitcnt vmcnt(3)" ::: "memory");
  body(NT - 2);
  asm volatile("s_waitcnt vmcnt(0)" ::: "memory");
  body(NT - 1);

  // ---- fused epilogue. C/D layout: col = lane&15, row = 4*(lane>>4) + reg ----
  long colbase = n0 + wn*64;                 // 64-aligned; block section-uniform
  if (colbase < 2048){
    // ---- Q path: rope, write q_r (B,H,S,64) ----
    int head = (int)(colbase >> 6);
    #pragma unroll
    for (int m = 0; m < 4; ++m)
      #pragma unroll
      for (int r = 0; r < 4; ++r){
        long srow = m0 + wm*64 + m*16 + 4*lg + r;   // = b*gS + s
        int b = (int)(srow >> 12), s = (int)(srow & 4095);
        const float* cp = cosb + srow*64;
        const float* sp = sinb + srow*64;
        unsigned short* op = q_r + ((size_t)(b*gH + head)*gS + s)*64;
        #pragma unroll
        for (int n = 0; n < 2; ++n){
          int d = n*16 + lr;
          float x1 = acc[m][n][r], x2 = acc[m][n+2][r];
          op[d]      = f2bf(x1*cp[d]    - x2*sp[d]);
          op[d+32]   = f2bf(x2*cp[d+32] + x1*sp[d+32]);
        }
      }
  } else if (colbase < 2560){
    // ---- K path: rope, write k_r (B,KVH,S,64) ----
    int head = (int)(colbase >> 6) - 32;
    #pragma unroll
    for (int m = 0; m < 4; ++m)
      #pragma unroll
      for (int r = 0; r < 4; ++r){
        long srow = m0 + wm*64 + m*16 + 4*lg + r;
        int b = (int)(srow >> 12), s = (int)(srow & 4095);
        const float* cp = cosb + srow*64;
        const float* sp = sinb + srow*64;
        unsigned short* op = k_r + ((size_t)(b*gKVH + head)*gS + s)*64;
        #pragma unroll
        for (int n = 0; n < 2; ++n){
          int d = n*16 + lr;
          float x1 = acc[m][n][r], x2 = acc[m][n+2][r];
          op[d]      = f2bf(x1*cp[d]    - x2*sp[d]);
          op[d+32]   = f2bf(x2*cp[d+32] + x1*sp[d+32]);
        }
      }
  } else {
    // ---- V path: plain, write vproj (B,S,512) ----
    #pragma unroll
    for (int m = 0; m < 4; ++m)
      #pragma unroll
      for (int r = 0; r < 4; ++r){
        long srow = m0 + wm*64 + m*16 + 4*lg + r;
        unsigned short* op = vproj + (size_t)srow*512 + (colbase - 2560);
        #pragma unroll
        for (int n = 0; n < 4; ++n)
          op[n*16 + lr] = f2bf(acc[m][n][r]);
      }
  }
}

// ---------------- GEMM 256x256 deep pipeline (Wo): C[M,N] = A[M,K] * B[N,K]^T ----------------
// Round-5 structure: 8 waves (2M x 4N), wave 128x64, BK=32, 4 x 32KB LDS buffers,
// depth-3 prefetch, counted vmcnt(8)/4/0, setprio, both-sides XOR swizzle.
// Grid 256 = 1 exact dispatch round.
template<int OUT_BF16>
__global__ __launch_bounds__(512, 2) void gemm256(const unsigned short* __restrict__ A,
                                                  const unsigned short* __restrict__ Bm,
                                                  void* __restrict__ Cout,
                                                  int Mdim, int Ndim, int Kdim)
{
  __shared__ unsigned short Sh[4*16384];   // buf s: A at s*16384 (256x32), B at +8192
  int tid = threadIdx.x, lane = tid & 63, w = tid >> 6, lr = lane & 15, lg = lane >> 4;
  int wm = w >> 2, wn = w & 3;
  int ntn = Ndim >> 8;
  int nwg = gridDim.x;
  int bid = (int)blockIdx.x;
  int swz = (bid & 7) * (nwg >> 3) + (bid >> 3);   // XCD-chunked (nwg % 8 == 0)
  long m0 = (long)(swz / ntn) * 256;
  long n0 = (long)(swz % ntn) * 256;
  int NT = Kdim >> 5;

  f32x4 acc[8][4] = {};

  auto stage = [&](int t){
    int sbase = (t & 3) * 16384;
    int k0 = t << 5;
    #pragma unroll
    for (int i = 0; i < 2; ++i){
      int c = w*64 + lane + i*512;             // chunk 0..1023 (256 rows x 4)
      int row = c >> 2;
      int colb = ((c & 3) << 4) ^ (((row >> 1) & 3) << 4);
      gload16((const char*)A + ((m0 + row) * (long)Kdim + k0) * 2 + colb,
              (void*)&Sh[sbase + (w*64 + i*512)*8]);
      gload16((const char*)Bm + ((n0 + row) * (long)Kdim + k0) * 2 + colb,
              (void*)&Sh[sbase + 8192 + (w*64 + i*512)*8]);
    }
  };

  auto body = [&](int t){
    int sb = (t & 3) * 16384;
    __builtin_amdgcn_s_barrier();
    if (t + 3 < NT) stage(t + 3);
    bf16x8 af[8], bfr[4];
    #pragma unroll
    for (int m = 0; m < 8; ++m){
      int row = wm*128 + m*16 + lr;
      af[m] = *(const bf16x8*)&Sh[sb + row*32 + ((lg ^ ((row >> 1) & 3)) << 3)];
    }
    #pragma unroll
    for (int n = 0; n < 4; ++n){
      int row = wn*64 + n*16 + lr;
      bfr[n] = *(const bf16x8*)&Sh[sb + 8192 + row*32 + ((lg ^ ((row >> 1) & 3)) << 3)];
    }
    __builtin_amdgcn_s_setprio(1);
    #pragma unroll
    for (int m = 0; m < 8; ++m)
      #pragma unroll
      for (int n = 0; n < 4; ++n)
        acc[m][n] = __builtin_amdgcn_mfma_f32_16x16x32_bf16(af[m], bfr[n], acc[m][n], 0, 0, 0);
    __builtin_amdgcn_s_setprio(0);
  };

  // prologue: tiles 0..2 in flight (12 loads/thread)
  stage(0); stage(1); stage(2);
  for (int t = 0; t < NT - 2; ++t){
    asm volatile("s_waitcnt vmcnt(8)" ::: "memory");
    body(t);
  }
  asm volatile("s_waitcnt vmcnt(4)" ::: "memory");
  body(NT - 2);
  asm volatile("s_waitcnt vmcnt(0)" ::: "memory");
  body(NT - 1);

  // epilogue: C/D layout col = lane&15, row = 4*(lane>>4) + reg
  #pragma unroll
  for (int m = 0; m < 8; ++m)
    #pragma unroll
    for (int n = 0; n < 4; ++n)
      #pragma unroll
      for (int r = 0; r < 4; ++r){
        long row = m0 + wm*128 + m*16 + 4*lg + r;
        long col = n0 + wn*64 + n*16 + lr;
        float v = acc[m][n][r];
        if (OUT_BF16) ((unsigned short*)Cout)[row*Ndim + col] = f2bf(v);
        else          ((float*)Cout)[row*Ndim + col] = v;
      }
}

// ---------------- 64x64 tile transpose -> d-major (B,KVH,64,S) ----------------
// mode 0: in = (B,KVH,S,64) rows (k_r).  mode 1: in = (B,S,tokStride) at +voff.
__global__ __launch_bounds__(256) void transpose64(const unsigned short* __restrict__ in,
                                                   unsigned short* __restrict__ out,
                                                   int tokStride, int voff, int mode)
{
  __shared__ unsigned short T[64*72];
  int bid = blockIdx.x;
  int st = bid & 63; int kvh = (bid >> 6) & 7; int b = bid >> 9;
  int s0 = st*64;
  int tid = threadIdx.x;
  const unsigned short* ip;
  size_t tokstr;
  if (mode == 0){ ip = in + ((size_t)(b*gKVH+kvh)*gS + s0)*64;                  tokstr = 64; }
  else          { ip = in + (size_t)(b*gS+s0)*tokStride + voff + kvh*64;        tokstr = tokStride; }
  #pragma unroll
  for (int i = 0; i < 2; ++i){
    int cc = tid + 256*i; int sl = cc >> 3, ch = cc & 7;
    *(uint4*)&T[sl*72 + ch*8] = *(const uint4*)&ip[(size_t)sl*tokstr + ch*8];
  }
  __syncthreads();
  unsigned short* op = out + ((size_t)(b*gKVH+kvh)*64)*gS;
  #pragma unroll
  for (int i = 0; i < 2; ++i){
    int cc = tid + 256*i; int d = cc >> 3, ch = cc & 7;
    unsigned short t[8];
    #pragma unroll
    for (int u = 0; u < 8; ++u) t[u] = T[(ch*8+u)*72 + d];
    *(uint4*)&op[(size_t)d*gS + s0 + ch*8] = pack8(t);
  }
}

// ---------------- local sliding-window attention ----------------
__global__ __launch_bounds__(256) void local_attn(const unsigned short* __restrict__ q_r,
                                                  const unsigned short* __restrict__ k_r,
                                                  const unsigned short* __restrict__ vt,
                                                  unsigned short* __restrict__ olocal)
{
  __shared__ unsigned short Qs[64*72];
  __shared__ unsigned short Ks[64*72];
  __shared__ unsigned short VTs[64*72];
  __shared__ unsigned short Ps[4*16*72];
  int bid = blockIdx.x;
  int qt = bid & 63; int h = (bid >> 6) & 31; int b = bid >> 11;
  int kvh = h >> 2;
  int q0 = qt*64;
  int tid = threadIdx.x, lane = tid & 63, w = tid >> 6, lr = lane & 15, lg = lane >> 4;
  const unsigned short* qp = q_r + ((size_t)(b*gH  +h  )*gS + q0)*64;
  const unsigned short* kp = k_r + ((size_t)(b*gKVH+kvh)*gS)*64;
  const unsigned short* vp = vt  + ((size_t)(b*gKVH+kvh)*64)*gS;   // rows d, stride S

  #pragma unroll
  for (int i = 0; i < 2; ++i){
    int cc = tid + 256*i; int row = cc >> 3, ch = cc & 7;
    *(uint4*)&Qs[row*72 + ch*8] = *(const uint4*)&qp[row*64 + ch*8];
  }
  float mrun[4], lsum[4];
  f32x4 accO[4] = {};
  #pragma unroll
  for (int r = 0; r < 4; ++r){ mrun[r] = -1e30f; lsum[r] = 0.f; }
  int wq = w*16;
  int kt0 = (q0 >= 256) ? 0 : ((256 - q0) >> 6);

  for (int kt = kt0; kt < 5; ++kt){
    int kb = q0 - 256 + kt*64;
    __syncthreads();
    #pragma unroll
    for (int i = 0; i < 2; ++i){
      int cc = tid + 256*i; int row = cc >> 3, ch = cc & 7;
      *(uint4*)&Ks[row*72 + ch*8]  = *(const uint4*)&kp[(size_t)(kb+row)*64 + ch*8];
      *(uint4*)&VTs[row*72 + ch*8] = *(const uint4*)&vp[(size_t)row*gS + kb + ch*8];
    }
    __syncthreads();

    f32x4 sc[4] = {};
    #pragma unroll
    for (int kk = 0; kk < 64; kk += 32){
      bf16x8 aq = *(const bf16x8*)&Qs[(wq+lr)*72 + kk + 8*lg];
      #pragma unroll
      for (int f = 0; f < 4; ++f){
        bf16x8 bk = *(const bf16x8*)&Ks[(f*16+lr)*72 + kk + 8*lg];
        sc[f] = __builtin_amdgcn_mfma_f32_16x16x32_bf16(aq, bk, sc[f], 0, 0, 0);
      }
    }
    float rmax[4]; bool keepM[4][4];
    #pragma unroll
    for (int r = 0; r < 4; ++r) rmax[r] = -1e30f;
    #pragma unroll
    for (int f = 0; f < 4; ++f)
      #pragma unroll
      for (int r = 0; r < 4; ++r){
        int i = wq + 4*lg + r;
        int j = kt*64 + f*16 + lr;
        bool keep = (j > i) && (j <= i + 256);
        keepM[f][r] = keep;
        float s = sc[f][r]*0.125f;
        s = keep ? s : -1e30f;
        sc[f][r] = s;
        rmax[r] = fmaxf(rmax[r], s);
      }
    #pragma unroll
    for (int off = 1; off < 16; off <<= 1)
      #pragma unroll
      for (int r = 0; r < 4; ++r) rmax[r] = fmaxf(rmax[r], __shfl_xor(rmax[r], off));
    float psum[4];
    #pragma unroll
    for (int r = 0; r < 4; ++r){
      float mn = fmaxf(mrun[r], rmax[r]);
      float al = __expf(mrun[r] - mn);
      mrun[r] = mn;
      lsum[r] *= al;
      #pragma unroll
      for (int dt = 0; dt < 4; ++dt) accO[dt][r] *= al;
      psum[r] = 0.f;
    }
    #pragma unroll
    for (int f = 0; f < 4; ++f)
      #pragma unroll
      for (int r = 0; r < 4; ++r){
        float p = keepM[f][r] ? __expf(sc[f][r] - mrun[r]) : 0.f;
        psum[r] += p;
        Ps[w*1152 + (4*lg + r)*72 + f*16 + lr] = f2bf(p);
      }
    #pragma unroll
    for (int off = 1; off < 16; off <<= 1)
      #pragma unroll
      for (int r = 0; r < 4; ++r) psum[r] += __shfl_xor(psum[r], off);
    #pragma unroll
    for (int r = 0; r < 4; ++r) lsum[r] += psum[r];
    // Ps write->read is same-wave LDS (in-order DS pipe) — no barrier needed.
    #pragma unroll
    for (int kk = 0; kk < 64; kk += 32){
      bf16x8 ap = *(const bf16x8*)&Ps[w*1152 + lr*72 + kk + 8*lg];
      #pragma unroll
      for (int dt = 0; dt < 4; ++dt){
        bf16x8 bv = *(const bf16x8*)&VTs[(dt*16+lr)*72 + kk + 8*lg];
        accO[dt] = __builtin_amdgcn_mfma_f32_16x16x32_bf16(ap, bv, accO[dt], 0, 0, 0);
      }
    }
  }
  #pragma unroll
  for (int dt = 0; dt < 4; ++dt)
    #pragma unroll
    for (int r = 0; r < 4; ++r){
      int s = q0 + wq + 4*lg + r;
      int d = dt*16 + lr;
      float o = accO[dt][r] / lsum[r];
      olocal[((size_t)(b*gS+s)*gH + h)*64 + d] = f2bf(0.5f * o);
    }
}

// ---------------- linear attention pass 1 ----------------
__global__ __launch_bounds__(256) void lin_pass1(const unsigned short* __restrict__ ktr,
                                                 const unsigned short* __restrict__ vt,
                                                 float* __restrict__ kvbuf, float* __restrict__ ksbuf)
{
  __shared__ unsigned short pkT[64*136];
  __shared__ unsigned short vT[64*136];
  int bid = blockIdx.x;
  int c = bid & 31; int kvh = (bid >> 5) & 7; int b = bid >> 8;
  int tid = threadIdx.x, lane = tid & 63, w = tid >> 6, lr = lane & 15, lg = lane >> 4;
  int s0 = c*128;
  const unsigned short* kp = ktr + ((size_t)(b*gKVH+kvh)*64)*gS;
  const unsigned short* vp = vt  + ((size_t)(b*gKVH+kvh)*64)*gS;
  #pragma unroll
  for (int i = 0; i < 4; ++i){
    int cc = tid + 256*i; int d = cc >> 4, ch = cc & 15;
    unsigned short t[8]; unpack8(*(const uint4*)&kp[(size_t)d*gS + s0 + ch*8], t);
    #pragma unroll
    for (int u = 0; u < 8; ++u) t[u] = f2bf(phi_f(bf2f(t[u])));
    *(uint4*)&pkT[d*136 + ch*8] = pack8(t);
    *(uint4*)&vT[d*136 + ch*8]  = *(const uint4*)&vp[(size_t)d*gS + s0 + ch*8];
  }
  __syncthreads();
  f32x4 acc[4] = {};
  #pragma unroll
  for (int kk = 0; kk < 128; kk += 32){
    bf16x8 a = *(const bf16x8*)&pkT[(16*w+lr)*136 + kk + 8*lg];
    #pragma unroll
    for (int et = 0; et < 4; ++et){
      bf16x8 bv = *(const bf16x8*)&vT[(16*et+lr)*136 + kk + 8*lg];
      acc[et] = __builtin_amdgcn_mfma_f32_16x16x32_bf16(a, bv, acc[et], 0, 0, 0);
    }
  }
  size_t base = (size_t)((b*gKVH+kvh)*gNC + c);
  float* kvp = kvbuf + base*4096;
  #pragma unroll
  for (int et = 0; et < 4; ++et)
    #pragma unroll
    for (int r = 0; r < 4; ++r)
      kvp[(16*w + 4*lg + r)*64 + 16*et + lr] = acc[et][r];   // d-major [d][e]
  if (tid < 64){
    float sum = 0.f;
    for (int k = 0; k < 128; ++k) sum += bf2f(pkT[tid*136 + k]);
    ksbuf[base*64 + tid] = sum;
  }
}

// ---------------- linear attention pass 2: exclusive scan; kv transposed to e-major ----------------
__global__ void lin_pass2(const float* __restrict__ kvin, float* __restrict__ kvout,
                          float* __restrict__ ksbuf){
  int t = blockIdx.x*256 + threadIdx.x;
  const int per = 4096 + 64;
  if (t >= gB*gKVH*per) return;
  int bh = t / per; int e = t % per;
  if (e < 4096){
    int d = e >> 6, ecol = e & 63;
    const float* p = kvin  + (size_t)bh*gNC*4096 + e;
    float* q       = kvout + (size_t)bh*gNC*4096 + ecol*64 + d;
    float acc = 0.f;
    for (int cix = 0; cix < gNC; ++cix){ float v = p[(size_t)cix*4096]; q[(size_t)cix*4096] = acc; acc += v; }
  } else {
    float* p = ksbuf + (size_t)bh*gNC*64 + (e - 4096);
    float acc = 0.f;
    for (int cix = 0; cix < gNC; ++cix){ float v = p[cix*64]; p[cix*64] = acc; acc += v; }
  }
}

// ---------------- linear attention pass 3 ----------------
__global__ __launch_bounds__(256) void lin_pass3(const unsigned short* __restrict__ q_r,
                                                 const unsigned short* __restrict__ k_r,
                                                 const unsigned short* __restrict__ vt,
                                                 const float* __restrict__ SprevT,
                                                 const float* __restrict__ zprev,
                                                 unsigned short* __restrict__ olin)
{
  __shared__ unsigned short pq[128*72];
  __shared__ unsigned short pk[64*72];
  __shared__ unsigned short Ph[128*72];
  __shared__ unsigned short vT[64*72];
  __shared__ unsigned short SpT[64*72];
  __shared__ float zp[64];

  int bid = blockIdx.x;
  int c = bid & 31; int h = (bid >> 5) & 31; int b = bid >> 10;
  int kvh = h >> 2;
  int tid = threadIdx.x, lane = tid & 63, w = tid >> 6, lr = lane & 15, lg = lane >> 4;
  int s0 = c*128;
  const unsigned short* qp = q_r + ((size_t)(b*gH  +h  )*gS + s0)*64;
  const unsigned short* kp = k_r + ((size_t)(b*gKVH+kvh)*gS + s0)*64;
  const unsigned short* vp = vt  + ((size_t)(b*gKVH+kvh)*64)*gS;
  const float* Sp  = SprevT + ((size_t)((b*gKVH+kvh)*gNC + c))*4096;
  const float* zpg = zprev  + ((size_t)((b*gKVH+kvh)*gNC + c))*64;

  #pragma unroll
  for (int i = 0; i < 4; ++i){
    int cc = tid + 256*i; int row = cc >> 3, d0 = (cc & 7)*8;
    unsigned short t[8]; unpack8(*(const uint4*)(qp + row*64 + d0), t);
    #pragma unroll
    for (int u = 0; u < 8; ++u) pq[row*72 + d0 + u] = f2bf(phi_f(bf2f(t[u])));
  }
  #pragma unroll
  for (int i = 0; i < 16; ++i){
    int f = tid + 256*i; int e = f >> 6, d = f & 63;
    SpT[e*72 + d] = f2bf(Sp[f]);
  }
  if (tid < 64) zp[tid] = zpg[tid];

  float den[2][4] = {};
  f32x4 accO[2][4] = {};

  for (int kh = 0; kh < 2; ++kh){
    __syncthreads();
    #pragma unroll
    for (int i = 0; i < 2; ++i){
      int cc = tid + 256*i; int kr = cc >> 3, d0 = (cc & 7)*8;
      unsigned short t[8]; unpack8(*(const uint4*)(kp + (kh*64+kr)*64 + d0), t);
      #pragma unroll
      for (int u = 0; u < 8; ++u) pk[kr*72 + d0 + u] = f2bf(phi_f(bf2f(t[u])));
      *(uint4*)&vT[kr*72 + d0] = *(const uint4*)&vp[(size_t)kr*gS + s0 + kh*64 + d0];
    }
    __syncthreads();

    f32x4 sc[2][4] = {};
    #pragma unroll
    for (int kk = 0; kk < 64; kk += 32){
      bf16x8 a[2];
      #pragma unroll
      for (int rt = 0; rt < 2; ++rt) a[rt] = *(const bf16x8*)&pq[(32*w+16*rt+lr)*72 + kk + 8*lg];
      #pragma unroll
      for (int ct = 0; ct < 4; ++ct){
        bf16x8 bk = *(const bf16x8*)&pk[(16*ct+lr)*72 + kk + 8*lg];
        #pragma unroll
        for (int rt = 0; rt < 2; ++rt)
          sc[rt][ct] = __builtin_amdgcn_mfma_f32_16x16x32_bf16(a[rt], bk, sc[rt][ct], 0, 0, 0);
      }
    }
    #pragma unroll
    for (int rt = 0; rt < 2; ++rt)
      #pragma unroll
      for (int ct = 0; ct < 4; ++ct)
        #pragma unroll
        for (int r = 0; r < 4; ++r){
          int qrow = 32*w + 16*rt + 4*lg + r;
          int krow = kh*64 + 16*ct + lr;
          float sv = (krow <= qrow) ? sc[rt][ct][r] : 0.f;
          den[rt][r] += sv;
          Ph[qrow*72 + 16*ct + lr] = f2bf(sv);
        }
    #pragma unroll
    for (int kk = 0; kk < 64; kk += 32){
      bf16x8 ap[2];
      #pragma unroll
      for (int rt = 0; rt < 2; ++rt) ap[rt] = *(const bf16x8*)&Ph[(32*w+16*rt+lr)*72 + kk + 8*lg];
      #pragma unroll
      for (int et = 0; et < 4; ++et){
        bf16x8 bv = *(const bf16x8*)&vT[(16*et+lr)*72 + kk + 8*lg];
        #pragma unroll
        for (int rt = 0; rt < 2; ++rt)
          accO[rt][et] = __builtin_amdgcn_mfma_f32_16x16x32_bf16(ap[rt], bv, accO[rt][et], 0, 0, 0);
      }
    }
  }
  #pragma unroll
  for (int kk = 0; kk < 64; kk += 32){
    bf16x8 a[2];
    #pragma unroll
    for (int rt = 0; rt < 2; ++rt) a[rt] = *(const bf16x8*)&pq[(32*w+16*rt+lr)*72 + kk + 8*lg];
    #pragma unroll
    for (int et = 0; et < 4; ++et){
      bf16x8 bs = *(const bf16x8*)&SpT[(16*et+lr)*72 + kk + 8*lg];
      #pragma unroll
      for (int rt = 0; rt < 2; ++rt)
        accO[rt][et] = __builtin_amdgcn_mfma_f32_16x16x32_bf16(a[rt], bs, accO[rt][et], 0, 0, 0);
    }
  }
  #pragma unroll
  for (int rt = 0; rt < 2; ++rt)
    #pragma unroll
    for (int r = 0; r < 4; ++r){
      int qrow = 32*w + 16*rt + 4*lg + r;
      float part = 0.f;
      #pragma unroll
      for (int u = 0; u < 4; ++u){
        int d = 4*lr + u;
        part += bf2f(pq[qrow*72 + d]) * zp[d];
      }
      den[rt][r] += part;
      #pragma unroll
      for (int off = 1; off < 16; off <<= 1)
        den[rt][r] += __shfl_xor(den[rt][r], off);
    }
  #pragma unroll
  for (int rt = 0; rt < 2; ++rt)
    #pragma unroll
    for (int et = 0; et < 4; ++et)
      #pragma unroll
      for (int r = 0; r < 4; ++r){
        int qrow = 32*w + 16*rt + 4*lg + r;
        int e = 16*et + lr;
        float o = accO[rt][et][r] / (den[rt][r] + 1e-6f);
        int s = s0 + qrow;
        olin[((size_t)(b*gS+s)*gH + h)*64 + e] = f2bf(0.5f * o);
      }
}

// ---------------- host launch ----------------
extern "C" void kernel_launch(void* const* d_in, const int* in_sizes, int n_in,
                              void* d_out, int out_size, void* d_ws, size_t ws_size,
                              hipStream_t stream)
{
  const float* hidden = (const float*)d_in[0];
  const float* cosb   = (const float*)d_in[1];
  const float* sinb   = (const float*)d_in[2];
  const float* Wq     = (const float*)d_in[3];
  const float* Wk     = (const float*)d_in[4];
  const float* Wv     = (const float*)d_in[5];
  const float* Wo     = (const float*)d_in[6];
  float* out = (float*)d_out;

  char* ws = (char*)d_ws;
  size_t off = 0;
  auto alloc = [&](size_t bytes)->void*{
    void* p = ws + off; off += (bytes + 255) & ~(size_t)255; return p;
  };
  unsigned short* hbf    = (unsigned short*)alloc((size_t)gBS*gHID*2);   // hidden bf16; reused as hybrid bf16
  unsigned short* wqkv   = (unsigned short*)alloc((size_t)3072*gHID*2);  // [Wq;Wk;Wv]
  unsigned short* wob    = (unsigned short*)alloc((size_t)gHID*gHID*2);
  unsigned short* vproj  = (unsigned short*)alloc((size_t)gBS*512*2);    // (B,S,KVH*64)
  unsigned short* q_r    = (unsigned short*)alloc((size_t)gBS*gHID*2);   // (B,H,S,64)
  unsigned short* k_r    = (unsigned short*)alloc((size_t)gBS*512*2);    // (B,KVH,S,64)
  unsigned short* ktr    = (unsigned short*)alloc((size_t)gBS*512*2);    // (B,KVH,64,S)
  unsigned short* vt     = (unsigned short*)alloc((size_t)gBS*512*2);    // (B,KVH,64,S)
  unsigned short* olocal = (unsigned short*)alloc((size_t)gBS*gHID*2);
  unsigned short* olin   = (unsigned short*)alloc((size_t)gBS*gHID*2);
  float* kvbuf           = (float*)alloc((size_t)gB*gKVH*gNC*4096*4);
  float* kvT             = (float*)alloc((size_t)gB*gKVH*gNC*4096*4);
  float* ksbuf           = (float*)alloc((size_t)gB*gKVH*gNC*64*4);

  auto cvt = [&](const float* in, unsigned short* o, int n){
    int nb = (n/4 + 255)/256; if (nb > 4096) nb = 4096;
    cvt_kernel<<<dim3(nb), dim3(256), 0, stream>>>(in, o, n);
  };
  cvt(hidden, hbf, gBS*gHID);
  cvt(Wq, wqkv, gHID*gHID);
  cvt(Wk, wqkv + (size_t)2048*gHID, 512*gHID);
  cvt(Wv, wqkv + (size_t)2560*gHID, 512*gHID);
  cvt(Wo, wob, gHID*gHID);

  // fused QKV projection + RoPE + layout (q_r, k_r, vproj)
  gemm_qkv<<<dim3(64*12), dim3(512), 0, stream>>>(hbf, wqkv, cosb, sinb, q_r, k_r, vproj);

  transpose64<<<dim3(gB*gKVH*64), dim3(256), 0, stream>>>(k_r,   ktr, 64,  0, 0);
  transpose64<<<dim3(gB*gKVH*64), dim3(256), 0, stream>>>(vproj, vt,  512, 0, 1);

  local_attn<<<dim3(gB*gH*64), dim3(256), 0, stream>>>(q_r, k_r, vt, olocal);
  lin_pass1<<<dim3(gB*gKVH*gNC), dim3(256), 0, stream>>>(ktr, vt, kvbuf, ksbuf);
  lin_pass2<<<dim3((gB*gKVH*(4096+64) + 255)/256), dim3(256), 0, stream>>>(kvbuf, kvT, ksbuf);
  lin_pass3<<<dim3(gB*gH*gNC), dim3(256), 0, stream>>>(q_r, k_r, vt, kvT, ksbuf, olin);

  combine_kernel<<<dim3(gBS*gHID/8/256), dim3(256), 0, stream>>>(olocal, olin, hbf, gBS*gHID/8);
  gemm256<0><<<dim3(32*8), dim3(512), 0, stream>>>(hbf, wob, (void*)out, 8192, 2048, 2048);
}